// Round 4
// baseline (576.791 us; speedup 1.0000x reference)
//
#include <hip/hip_runtime.h>
#include <hip/hip_bf16.h>
#include <cstdint>
#include <cstddef>

// ---------------------------------------------------------------------------
// CausalSelfAttention fused block, MI355X/gfx950.  Round 4:
//  - attn: 2-term S (drop Qh*Kl), K via global_load_lds + slot-XOR swizzle,
//    P aliased into K LDS (34.8KB -> 4 blocks/CU), V-reg prefetch, defer-max,
//    exp2-domain softmax (scale folded into q at epilogue)
//  - QKV projections merged into one N=3072 GEMM; XCD swizzle on GEMM grids
// B=2 T=2048 D=2048 NH=16 NKV=4 HD=128 ROPE=64.
// ---------------------------------------------------------------------------

typedef __bf16 bf16_t;
typedef bf16_t bf16x8 __attribute__((ext_vector_type(8)));
typedef float f32x4 __attribute__((ext_vector_type(4)));

#define MFMA16(a, b, c) __builtin_amdgcn_mfma_f32_16x16x32_bf16((a), (b), (c), 0, 0, 0)

__device__ __forceinline__ bf16_t to_bf16(float f) {
  __hip_bfloat16 h = __float2bfloat16(f);
  return *reinterpret_cast<bf16_t*>(&h);
}

__device__ __forceinline__ void gload16(const bf16_t* g, bf16_t* l) {
  auto lds_ptr = reinterpret_cast<__attribute__((address_space(3))) unsigned int*>(
      reinterpret_cast<uintptr_t>(l));
  auto g_ptr = reinterpret_cast<const __attribute__((address_space(1))) unsigned int*>(
      reinterpret_cast<uintptr_t>(g));
  __builtin_amdgcn_global_load_lds(g_ptr, lds_ptr, 16, 0, 0);
}

// ---------------------------------------------------------------------------
// fp32 -> bf16 cast, vectorized
// ---------------------------------------------------------------------------
__global__ void k_cast_bf16(const float* __restrict__ in, bf16_t* __restrict__ o, long n) {
  long i = ((long)blockIdx.x * blockDim.x + threadIdx.x) * 4;
  const long step = (long)gridDim.x * blockDim.x * 4;
  for (; i < n; i += step) {
    const float4 v = *reinterpret_cast<const float4*>(in + i);
    bf16_t r[4] = {to_bf16(v.x), to_bf16(v.y), to_bf16(v.z), to_bf16(v.w)};
    *reinterpret_cast<uint64_t*>(o + i) = *reinterpret_cast<const uint64_t*>(r);
  }
}

// ---------------------------------------------------------------------------
// x split: in [4096][2048] fp32 -> x3 [4096][6144] bf16 = [xh | xl | xh]
// ---------------------------------------------------------------------------
__global__ void k_split_x(const float* __restrict__ in, bf16_t* __restrict__ x3) {
  long i = ((long)blockIdx.x * blockDim.x + threadIdx.x) * 4;
  const long step = (long)gridDim.x * blockDim.x * 4;
  for (; i < (long)4096 * 2048; i += step) {
    const float4 v = *reinterpret_cast<const float4*>(in + i);
    const long row = i >> 11, col = i & 2047;
    bf16_t h[4], l[4];
    const float vv[4] = {v.x, v.y, v.z, v.w};
#pragma unroll
    for (int j = 0; j < 4; ++j) {
      h[j] = to_bf16(vv[j]);
      l[j] = to_bf16(vv[j] - (float)h[j]);
    }
    const uint64_t h64 = *reinterpret_cast<const uint64_t*>(h);
    bf16_t* rp = x3 + row * 6144;
    *reinterpret_cast<uint64_t*>(rp + col) = h64;
    *reinterpret_cast<uint64_t*>(rp + 2048 + col) = *reinterpret_cast<const uint64_t*>(l);
    *reinterpret_cast<uint64_t*>(rp + 4096 + col) = h64;
  }
}

// ---------------------------------------------------------------------------
// W split: W [R][2048] fp32 -> w3 [R][6144] = [Wh | Wh | Wl]
// ---------------------------------------------------------------------------
__global__ void k_split_w(const float* __restrict__ W, bf16_t* __restrict__ w3, long n) {
  long i = ((long)blockIdx.x * blockDim.x + threadIdx.x) * 4;
  const long step = (long)gridDim.x * blockDim.x * 4;
  for (; i < n; i += step) {
    const float4 v = *reinterpret_cast<const float4*>(W + i);
    const long row = i >> 11, col = i & 2047;
    bf16_t h[4], l[4];
    const float vv[4] = {v.x, v.y, v.z, v.w};
#pragma unroll
    for (int j = 0; j < 4; ++j) {
      h[j] = to_bf16(vv[j]);
      l[j] = to_bf16(vv[j] - (float)h[j]);
    }
    const uint64_t h64 = *reinterpret_cast<const uint64_t*>(h);
    bf16_t* rp = w3 + row * 6144;
    *reinterpret_cast<uint64_t*>(rp + col) = h64;
    *reinterpret_cast<uint64_t*>(rp + 2048 + col) = h64;
    *reinterpret_cast<uint64_t*>(rp + 4096 + col) = *reinterpret_cast<const uint64_t*>(l);
  }
}

// ---------------------------------------------------------------------------
// RoPE cos/sin table: [T=2048][32]
// ---------------------------------------------------------------------------
__global__ void k_rope_tab(float* __restrict__ ctab, float* __restrict__ stab) {
  const int idx = blockIdx.x * blockDim.x + threadIdx.x;
  if (idx >= 2048 * 32) return;
  const int t = idx >> 5, i = idx & 31;
  const float freq = exp2f(-(float)i * 0.2076205059304601f);  // 10000^(-i/64)
  const float f = (float)t * freq;
  ctab[idx] = cosf(f);
  stab[idx] = sinf(f);
}

// ---------------------------------------------------------------------------
// NT GEMM: C[m,n] = sum_k A[m,k]*B[n,k].  Row strides lda/ldb (elements).
// 128x128 tile, BK=32, 4 waves, double-buffered LDS via global_load_lds(16B),
// XOR slot swizzle.  XCD-chunk block swizzle (requires nwg % 8 == 0).
// ---------------------------------------------------------------------------
__global__ __launch_bounds__(256, 2) void k_gemm_bt(
    const bf16_t* __restrict__ A, const bf16_t* __restrict__ Bm,
    float* __restrict__ C, int M, int N, int K, int lda, int ldb)
{
  __shared__ __align__(16) bf16_t lsA[2][128 * 32];
  __shared__ __align__(16) bf16_t lsB[2][128 * 32];
  const int tid = threadIdx.x;
  const int w = tid >> 6, l = tid & 63;
  const int lrow = l & 15, lk = l >> 4;
  // XCD-aware swizzle of the flattened grid (nwg multiple of 8)
  const int nwg = gridDim.x * gridDim.y;
  int lin = blockIdx.y * gridDim.x + blockIdx.x;
  lin = (lin & 7) * (nwg >> 3) + (lin >> 3);
  const int m0 = (lin / gridDim.x) * 128, n0 = (lin % gridDim.x) * 128;
  const int wm = w >> 1, wn = w & 1;

  const int r0 = tid >> 2;
  const int sl = tid & 3;
  const int ls0 = sl ^ ((r0 >> 1) & 3);
  const int r1 = r0 + 64;
  const int ls1 = sl ^ ((r1 >> 1) & 3);
  const bf16_t* gA0 = A + (size_t)(m0 + r0) * lda + ls0 * 8;
  const bf16_t* gA1 = A + (size_t)(m0 + r1) * lda + ls1 * 8;
  const bf16_t* gB0 = Bm + (size_t)(n0 + r0) * ldb + ls0 * 8;
  const bf16_t* gB1 = Bm + (size_t)(n0 + r1) * ldb + ls1 * 8;
  const int lofs = tid * 8;

  f32x4 acc[4][4] = {};
  const int nkt = K >> 5;

  gload16(gA0, &lsA[0][lofs]);
  gload16(gA1, &lsA[0][lofs + 2048]);
  gload16(gB0, &lsB[0][lofs]);
  gload16(gB1, &lsB[0][lofs + 2048]);
  __syncthreads();

  for (int kt = 0; kt < nkt; ++kt) {
    const int buf = kt & 1;
    if (kt + 1 < nkt) {
      const int ko = (kt + 1) << 5;
      gload16(gA0 + ko, &lsA[buf ^ 1][lofs]);
      gload16(gA1 + ko, &lsA[buf ^ 1][lofs + 2048]);
      gload16(gB0 + ko, &lsB[buf ^ 1][lofs]);
      gload16(gB1 + ko, &lsB[buf ^ 1][lofs + 2048]);
    }
    bf16x8 af[4], bfv[4];
#pragma unroll
    for (int mi = 0; mi < 4; ++mi) {
      const int r = wm * 64 + mi * 16 + lrow;
      const int ps = lk ^ ((r >> 1) & 3);
      af[mi] = *reinterpret_cast<const bf16x8*>(&lsA[buf][r * 32 + ps * 8]);
    }
#pragma unroll
    for (int ni = 0; ni < 4; ++ni) {
      const int r = wn * 64 + ni * 16 + lrow;
      const int ps = lk ^ ((r >> 1) & 3);
      bfv[ni] = *reinterpret_cast<const bf16x8*>(&lsB[buf][r * 32 + ps * 8]);
    }
#pragma unroll
    for (int mi = 0; mi < 4; ++mi)
#pragma unroll
      for (int ni = 0; ni < 4; ++ni)
        acc[mi][ni] = MFMA16(af[mi], bfv[ni], acc[mi][ni]);
    __syncthreads();
  }

  // C/D layout: col = lane&15, row = (lane>>4)*4 + reg
#pragma unroll
  for (int mi = 0; mi < 4; ++mi) {
    const int row = m0 + wm * 64 + mi * 16 + lk * 4;
#pragma unroll
    for (int ni = 0; ni < 4; ++ni) {
      const int col = n0 + wn * 64 + ni * 16 + lrow;
#pragma unroll
      for (int rg = 0; rg < 4; ++rg)
        C[(size_t)(row + rg) * N + col] = acc[mi][ni][rg];
    }
  }
}

// ---------------------------------------------------------------------------
// QKV epilogue.  qkv raw = [4096][3072] f32 (q 0..2047 | k 2048..2559 |
// v 2560..3071).  RMS-norm(q,k) + partial RoPE in fp32; q gets
// gain*(1/sqrt(128))*log2(e) folded in, stored hi/lo bf16 [.][256];
// k plain bf16 [.][128]; v += ve_embed, plain bf16.
// ---------------------------------------------------------------------------
__global__ __launch_bounds__(256) void k_qkv_epi(
    const float* __restrict__ qkv, const float* __restrict__ ve,
    const float* __restrict__ qgain,
    const float* __restrict__ ctab, const float* __restrict__ stab,
    bf16_t* __restrict__ qn2, bf16_t* __restrict__ kn, bf16_t* __restrict__ vn)
{
  const int blk = blockIdx.x;           // b*2048 + t
  const int b = blk >> 11, t = blk & 2047;
  const int w = threadIdx.x >> 6, l = threadIdx.x & 63;
  const int i32 = l & 31;
  const float c = ctab[t * 32 + i32], s = stab[t * 32 + i32];
  const float EPS = 1.1920929e-07f;
  constexpr float SCALE_L2E = 0.088388347648318447f * 1.4426950408889634f;

  // Q: wave w handles heads w, w+4, w+8, w+12
#pragma unroll
  for (int it = 0; it < 4; ++it) {
    const int h = w + it * 4;
    const float* row = qkv + (size_t)blk * 3072 + h * 128;
    float x0 = row[l], x1 = row[l + 64];
    float ss = x0 * x0 + x1 * x1;
#pragma unroll
    for (int off = 32; off; off >>= 1) ss += __shfl_xor(ss, off);
    const float rn = rsqrtf(ss * (1.0f / 128.0f) + EPS);
    x0 *= rn; x1 *= rn;
    const float p = __shfl_xor(x0, 32);
    float xr = (l < 32) ? (x0 * c - p * s) : (p * s + x0 * c);
    const float g = qgain[h] * SCALE_L2E;
    xr *= g; x1 *= g;
    bf16_t* orow = qn2 + (((size_t)(b * 16 + h)) * 2048 + t) * 256;
    const bf16_t h0 = to_bf16(xr), h1 = to_bf16(x1);
    orow[l] = h0;        orow[128 + l] = to_bf16(xr - (float)h0);
    orow[l + 64] = h1;   orow[192 + l] = to_bf16(x1 - (float)h1);
  }
  // K: wave w -> kv head w (plain bf16)
  {
    const float* row = qkv + (size_t)blk * 3072 + 2048 + w * 128;
    float x0 = row[l], x1 = row[l + 64];
    float ss = x0 * x0 + x1 * x1;
#pragma unroll
    for (int off = 32; off; off >>= 1) ss += __shfl_xor(ss, off);
    const float rn = rsqrtf(ss * (1.0f / 128.0f) + EPS);
    x0 *= rn; x1 *= rn;
    const float p = __shfl_xor(x0, 32);
    const float xr = (l < 32) ? (x0 * c - p * s) : (p * s + x0 * c);
    bf16_t* orow = kn + (((size_t)(b * 4 + w)) * 2048 + t) * 128;
    orow[l] = to_bf16(xr);
    orow[l + 64] = to_bf16(x1);
  }
  // V: wave w -> kv head w ; v = vraw + ve
  {
    const float* row = qkv + (size_t)blk * 3072 + 2560 + w * 128;
    const float* verow = ve + (size_t)blk * 512 + w * 128;
    bf16_t* orow = vn + (((size_t)(b * 4 + w)) * 2048 + t) * 128;
    orow[l] = to_bf16(row[l] + verow[l]);
    orow[l + 64] = to_bf16(row[l + 64] + verow[l + 64]);
  }
}

// ---------------------------------------------------------------------------
// Causal GQA flash attention.  q hi/lo (2-term S), k plain.  QBLK=64 (4 waves
// x 16 q-rows), KVBLK=64, longest-qt-first.
// LDS: lsK [64][128] via global_load_lds w/ slot^=(row&7) swizzle (16KB);
//      per-wave P [16][64] col^=(row&7)<<3 aliased into lsK; lsV^T [128][72].
// Softmax in log2 domain (scale folded into q), defer-max THR=8.
// ---------------------------------------------------------------------------
__global__ __launch_bounds__(256, 4) void k_attn(
    const bf16_t* __restrict__ qn2, const bf16_t* __restrict__ kn,
    const bf16_t* __restrict__ vn, bf16_t* __restrict__ y)
{
  __shared__ __align__(16) bf16_t lsK[64 * 128];   // 16384 B (P aliases 0..8191)
  __shared__ __align__(16) bf16_t lsV[128 * 72];   // 18432 B
  const int qt = 31 - (int)blockIdx.y;  // longest first
  const int bh = blockIdx.x;            // 0..31
  const int b = bh >> 4, h = bh & 15, kvh = h >> 2;
  const int tid = threadIdx.x, w = tid >> 6, l = tid & 63;
  const int lrow = l & 15, lk = l >> 4;
  const int qbase = qt * 64 + w * 16;
  constexpr float NEG = -1e30f;
  bf16_t* lsP = lsK + w * 1024;         // per-wave [16][64] swizzled

  // Q fragments (A-frag: row = lane&15, k = lk*8+j), hi and lo
  const bf16_t* qp = qn2 + ((size_t)(b * 16 + h) * 2048) * 256;
  bf16x8 aQh[4], aQl[4];
#pragma unroll
  for (int kf = 0; kf < 4; ++kf) {
    const size_t base = (size_t)(qbase + lrow) * 256 + kf * 32 + lk * 8;
    aQh[kf] = *reinterpret_cast<const bf16x8*>(qp + base);
    aQl[kf] = *reinterpret_cast<const bf16x8*>(qp + base + 128);
  }

  const bf16_t* kp = kn + ((size_t)(b * 4 + kvh) * 2048) * 128;
  const bf16_t* vp = vn + ((size_t)(b * 4 + kvh) * 2048) * 128;

  f32x4 o[8] = {};
  float mst[4], lst[4];
#pragma unroll
  for (int rg = 0; rg < 4; ++rg) { mst[rg] = NEG; lst[rg] = 0.f; }

  // V-reg prefetch state (tile t0): vreg[it] covers kv=cch>>4, d=(cch&15)*8
  bf16x8 vreg[4];
  auto loadV = [&](int t0) {
#pragma unroll
    for (int it = 0; it < 4; ++it) {
      const int cch = tid + it * 256;
      vreg[it] = *reinterpret_cast<const bf16x8*>(
          vp + (size_t)(t0 + (cch >> 4)) * 128 + (cch & 15) * 8);
    }
  };
  loadV(0);

  const int ntiles = qt + 1;
  for (int tt = 0; tt < ntiles; ++tt) {
    const int t0 = tt * 64;
    __syncthreads();  // prior tile's P/V reads done
    // stage K via global_load_lds, source slot pre-swizzled: slot ^= (row&7)
#pragma unroll
    for (int it = 0; it < 4; ++it) {
      const int r = it * 16 + (tid >> 4);
      const int slot = (tid & 15) ^ (r & 7);
      gload16(kp + (size_t)(t0 + r) * 128 + slot * 8, lsK + it * 2048 + tid * 8);
    }
    // V^T [128 d][72], col' = kv ^ ((dg&7)<<3), from prefetched regs
#pragma unroll
    for (int it = 0; it < 4; ++it) {
      const int cch = tid + it * 256;
      const int kv = cch >> 4, dg = cch & 15;
      const int colb = kv ^ ((dg & 7) << 3);
#pragma unroll
      for (int j = 0; j < 8; ++j) lsV[(dg * 8 + j) * 72 + colb] = vreg[it][j];
    }
    __syncthreads();  // barrier drains vmcnt -> K resident

    // S = Qh*Kh + Ql*Kh  (16 q-rows x 64 kv), K read with slot-XOR
    f32x4 sacc[4] = {};
#pragma unroll
    for (int cf = 0; cf < 4; ++cf) {
      const int krow = cf * 16 + lrow;
#pragma unroll
      for (int kf = 0; kf < 4; ++kf) {
        const bf16x8 bK = *reinterpret_cast<const bf16x8*>(
            &lsK[krow * 128 + (((kf * 4 + lk) ^ (lrow & 7)) << 3)]);
        sacc[cf] = MFMA16(aQh[kf], bK, sacc[cf]);
        sacc[cf] = MFMA16(aQl[kf], bK, sacc[cf]);
      }
    }
    __syncthreads();  // all waves done reading K before P overwrites it

    // prefetch next tile's V (hides under softmax+PV)
    if (tt + 1 < ntiles) loadV(t0 + 64);

    // online softmax, log2 domain; mask only on diagonal tile
    if (tt == qt) {
#pragma unroll
      for (int rg = 0; rg < 4; ++rg) {
        const int qi = w * 16 + lk * 4 + rg;  // within-tile row
#pragma unroll
        for (int cf = 0; cf < 4; ++cf)
          if (cf * 16 + lrow > qi) sacc[cf][rg] = NEG;
      }
    }
    float pmax[4];
#pragma unroll
    for (int rg = 0; rg < 4; ++rg) {
      float mx = fmaxf(fmaxf(sacc[0][rg], sacc[1][rg]),
                       fmaxf(sacc[2][rg], sacc[3][rg]));
      mx = fmaxf(mx, __shfl_xor(mx, 1));
      mx = fmaxf(mx, __shfl_xor(mx, 2));
      mx = fmaxf(mx, __shfl_xor(mx, 4));
      mx = fmaxf(mx, __shfl_xor(mx, 8));
      pmax[rg] = mx;
    }
    const bool grow = (pmax[0] > mst[0] + 8.f) | (pmax[1] > mst[1] + 8.f) |
                      (pmax[2] > mst[2] + 8.f) | (pmax[3] > mst[3] + 8.f);
    if (__any(grow)) {
#pragma unroll
      for (int rg = 0; rg < 4; ++rg) {
        const float mnew = fmaxf(mst[rg], pmax[rg]);
        const float alpha = exp2f(mst[rg] - mnew);
        mst[rg] = mnew;
        lst[rg] *= alpha;
#pragma unroll
        for (int df = 0; df < 8; ++df) o[df][rg] *= alpha;
      }
    }
#pragma unroll
    for (int rg = 0; rg < 4; ++rg) {
      float rsum = 0.f;
#pragma unroll
      for (int cf = 0; cf < 4; ++cf) {
        const float p = exp2f(sacc[cf][rg] - mst[rg]);
        sacc[cf][rg] = p;
        rsum += p;
      }
      rsum += __shfl_xor(rsum, 1);
      rsum += __shfl_xor(rsum, 2);
      rsum += __shfl_xor(rsum, 4);
      rsum += __shfl_xor(rsum, 8);
      lst[rg] += rsum;
    }

    // P -> per-wave swizzled LDS [16][64]: col' = col ^ ((row&7)<<3)
#pragma unroll
    for (int cf = 0; cf < 4; ++cf)
#pragma unroll
      for (int rg = 0; rg < 4; ++rg) {
        const int prow = lk * 4 + rg;
        lsP[prow * 64 + ((cf * 16 + lrow) ^ ((prow & 7) << 3))] =
            to_bf16(sacc[cf][rg]);
      }
    // PV
#pragma unroll
    for (int k2 = 0; k2 < 2; ++k2) {
      const bf16x8 aP = *reinterpret_cast<const bf16x8*>(
          &lsP[lrow * 64 + ((k2 * 32 + lk * 8) ^ ((lrow & 7) << 3))]);
#pragma unroll
      for (int df = 0; df < 8; ++df) {
        const int row = df * 16 + lrow;
        const int colb = (k2 * 32 + lk * 8) ^ (((row >> 3) & 7) << 3);
        const bf16x8 bV = *reinterpret_cast<const bf16x8*>(&lsV[row * 72 + colb]);
        o[df] = MFMA16(aP, bV, o[df]);
      }
    }
  }

  // normalize + write y [b][t][h*128+d]
#pragma unroll
  for (int rg = 0; rg < 4; ++rg) {
    const float inv = 1.0f / lst[rg];
    const int qi = qbase + lk * 4 + rg;
    const size_t rowoff = ((size_t)(b * 2048 + qi)) * 2048 + h * 128;
#pragma unroll
    for (int df = 0; df < 8; ++df)
      y[rowoff + df * 16 + lrow] = to_bf16(o[df][rg] * inv);
  }
}

// ---------------------------------------------------------------------------
extern "C" void kernel_launch(void* const* d_in, const int* in_sizes, int n_in,
                              void* d_out, int out_size, void* d_ws, size_t ws_size,
                              hipStream_t stream) {
  const float* x  = (const float*)d_in[0];
  const float* ve = (const float*)d_in[1];
  const float* Wq = (const float*)d_in[2];
  const float* Wk = (const float*)d_in[3];
  const float* Wv = (const float*)d_in[4];
  const float* Wp = (const float*)d_in[5];
  const float* qg = (const float*)d_in[6];
  float* out = (float*)d_out;

  char* ws = (char*)d_ws;
  size_t off = 0;
  auto alloc = [&](size_t bytes) -> char* {
    char* p = ws + off;
    off += (bytes + 255) & ~(size_t)255;
    return p;
  };

  bf16_t* x3     = (bf16_t*)alloc((size_t)4096 * 6144 * 2);  // [xh|xl|xh]; later qn2
  bf16_t* wqkv3  = (bf16_t*)alloc((size_t)3072 * 6144 * 2);  // rows: Wq|Wk|Wv, [Wh|Wh|Wl]
  bf16_t* wpb    = (bf16_t*)alloc((size_t)2048 * 2048 * 2);
  float*  qkvraw = (float*)alloc((size_t)4096 * 3072 * 4);   // later yb
  bf16_t* kn     = (bf16_t*)alloc((size_t)2 * 4 * 2048 * 128 * 2);
  bf16_t* vn     = (bf16_t*)alloc((size_t)2 * 4 * 2048 * 128 * 2);
  float*  ctab   = (float*)alloc((size_t)2048 * 32 * 4);
  float*  stab   = (float*)alloc((size_t)2048 * 32 * 4);
  bf16_t* qn2    = x3;               // x3 dead after QKV GEMM
  bf16_t* yb     = (bf16_t*)qkvraw;  // qkvraw dead after epilogue
  (void)ws_size; (void)in_sizes; (void)n_in; (void)out_size;

  k_split_x<<<2048, 256, 0, stream>>>(x, x3);
  k_split_w<<<1024, 256, 0, stream>>>(Wq, wqkv3, (long)2048 * 2048);
  k_split_w<<<512,  256, 0, stream>>>(Wk, wqkv3 + (size_t)2048 * 6144, (long)512 * 2048);
  k_split_w<<<512,  256, 0, stream>>>(Wv, wqkv3 + (size_t)2560 * 6144, (long)512 * 2048);
  k_cast_bf16<<<1024, 256, 0, stream>>>(Wp, wpb, (long)2048 * 2048);
  k_rope_tab<<<256, 256, 0, stream>>>(ctab, stab);

  // qkvraw = [xh|xl|xh]·[Wh|Wh|Wl]^T  (single pass, M=4096 N=3072 K=6144)
  k_gemm_bt<<<dim3(24, 32), 256, 0, stream>>>(x3, wqkv3, qkvraw, 4096, 3072, 6144, 6144, 6144);

  k_qkv_epi<<<4096, 256, 0, stream>>>(qkvraw, ve, qg, ctab, stab, qn2, kn, vn);

  k_attn<<<dim3(32, 32), 256, 0, stream>>>(qn2, kn, vn, yb);

  k_gemm_bt<<<dim3(16, 32), 256, 0, stream>>>(yb, wpb, out, 4096, 2048, 2048, 2048, 2048);
}

// Round 5
// 378.819 us; speedup vs baseline: 1.5226x; 1.5226x over previous
//
#include <hip/hip_runtime.h>
#include <hip/hip_bf16.h>
#include <cstdint>
#include <cstddef>

// ---------------------------------------------------------------------------
// CausalSelfAttention fused block, MI355X/gfx950.  Round 5:
//  - attn: K back to reg-staged padded LDS [64][136] (2-way reads; R4's
//    gload_lds slot-XOR was 8-way + broke L2 reuse), K+V reg prefetch one
//    tile ahead, separate P buffer -> 2 barriers/tile, 3 blocks/CU.
//  - keep: 2-term S (q hi/lo, k plain), exp2-domain softmax w/ folded scale,
//    defer-max, diagonal-only mask, longest-first, merged QKV GEMM, XCD swz.
// B=2 T=2048 D=2048 NH=16 NKV=4 HD=128 ROPE=64.
// ---------------------------------------------------------------------------

typedef __bf16 bf16_t;
typedef bf16_t bf16x8 __attribute__((ext_vector_type(8)));
typedef float f32x4 __attribute__((ext_vector_type(4)));

#define MFMA16(a, b, c) __builtin_amdgcn_mfma_f32_16x16x32_bf16((a), (b), (c), 0, 0, 0)

__device__ __forceinline__ bf16_t to_bf16(float f) {
  __hip_bfloat16 h = __float2bfloat16(f);
  return *reinterpret_cast<bf16_t*>(&h);
}

__device__ __forceinline__ void gload16(const bf16_t* g, bf16_t* l) {
  auto lds_ptr = reinterpret_cast<__attribute__((address_space(3))) unsigned int*>(
      reinterpret_cast<uintptr_t>(l));
  auto g_ptr = reinterpret_cast<const __attribute__((address_space(1))) unsigned int*>(
      reinterpret_cast<uintptr_t>(g));
  __builtin_amdgcn_global_load_lds(g_ptr, lds_ptr, 16, 0, 0);
}

// ---------------------------------------------------------------------------
// fp32 -> bf16 cast, vectorized
// ---------------------------------------------------------------------------
__global__ void k_cast_bf16(const float* __restrict__ in, bf16_t* __restrict__ o, long n) {
  long i = ((long)blockIdx.x * blockDim.x + threadIdx.x) * 4;
  const long step = (long)gridDim.x * blockDim.x * 4;
  for (; i < n; i += step) {
    const float4 v = *reinterpret_cast<const float4*>(in + i);
    bf16_t r[4] = {to_bf16(v.x), to_bf16(v.y), to_bf16(v.z), to_bf16(v.w)};
    *reinterpret_cast<uint64_t*>(o + i) = *reinterpret_cast<const uint64_t*>(r);
  }
}

// ---------------------------------------------------------------------------
// x split: in [4096][2048] fp32 -> x3 [4096][6144] bf16 = [xh | xl | xh]
// ---------------------------------------------------------------------------
__global__ void k_split_x(const float* __restrict__ in, bf16_t* __restrict__ x3) {
  long i = ((long)blockIdx.x * blockDim.x + threadIdx.x) * 4;
  const long step = (long)gridDim.x * blockDim.x * 4;
  for (; i < (long)4096 * 2048; i += step) {
    const float4 v = *reinterpret_cast<const float4*>(in + i);
    const long row = i >> 11, col = i & 2047;
    bf16_t h[4], l[4];
    const float vv[4] = {v.x, v.y, v.z, v.w};
#pragma unroll
    for (int j = 0; j < 4; ++j) {
      h[j] = to_bf16(vv[j]);
      l[j] = to_bf16(vv[j] - (float)h[j]);
    }
    const uint64_t h64 = *reinterpret_cast<const uint64_t*>(h);
    bf16_t* rp = x3 + row * 6144;
    *reinterpret_cast<uint64_t*>(rp + col) = h64;
    *reinterpret_cast<uint64_t*>(rp + 2048 + col) = *reinterpret_cast<const uint64_t*>(l);
    *reinterpret_cast<uint64_t*>(rp + 4096 + col) = h64;
  }
}

// ---------------------------------------------------------------------------
// W split: W [R][2048] fp32 -> w3 [R][6144] = [Wh | Wh | Wl]
// ---------------------------------------------------------------------------
__global__ void k_split_w(const float* __restrict__ W, bf16_t* __restrict__ w3, long n) {
  long i = ((long)blockIdx.x * blockDim.x + threadIdx.x) * 4;
  const long step = (long)gridDim.x * blockDim.x * 4;
  for (; i < n; i += step) {
    const float4 v = *reinterpret_cast<const float4*>(W + i);
    const long row = i >> 11, col = i & 2047;
    bf16_t h[4], l[4];
    const float vv[4] = {v.x, v.y, v.z, v.w};
#pragma unroll
    for (int j = 0; j < 4; ++j) {
      h[j] = to_bf16(vv[j]);
      l[j] = to_bf16(vv[j] - (float)h[j]);
    }
    const uint64_t h64 = *reinterpret_cast<const uint64_t*>(h);
    bf16_t* rp = w3 + row * 6144;
    *reinterpret_cast<uint64_t*>(rp + col) = h64;
    *reinterpret_cast<uint64_t*>(rp + 2048 + col) = h64;
    *reinterpret_cast<uint64_t*>(rp + 4096 + col) = *reinterpret_cast<const uint64_t*>(l);
  }
}

// ---------------------------------------------------------------------------
// RoPE cos/sin table: [T=2048][32]
// ---------------------------------------------------------------------------
__global__ void k_rope_tab(float* __restrict__ ctab, float* __restrict__ stab) {
  const int idx = blockIdx.x * blockDim.x + threadIdx.x;
  if (idx >= 2048 * 32) return;
  const int t = idx >> 5, i = idx & 31;
  const float freq = exp2f(-(float)i * 0.2076205059304601f);  // 10000^(-i/64)
  const float f = (float)t * freq;
  ctab[idx] = cosf(f);
  stab[idx] = sinf(f);
}

// ---------------------------------------------------------------------------
// NT GEMM: C[m,n] = sum_k A[m,k]*B[n,k].  Row strides lda/ldb (elements).
// 128x128 tile, BK=32, 4 waves, double-buffered LDS via global_load_lds(16B),
// XOR slot swizzle.  XCD-chunk block swizzle (requires nwg % 8 == 0).
// ---------------------------------------------------------------------------
__global__ __launch_bounds__(256, 2) void k_gemm_bt(
    const bf16_t* __restrict__ A, const bf16_t* __restrict__ Bm,
    float* __restrict__ C, int M, int N, int K, int lda, int ldb)
{
  __shared__ __align__(16) bf16_t lsA[2][128 * 32];
  __shared__ __align__(16) bf16_t lsB[2][128 * 32];
  const int tid = threadIdx.x;
  const int w = tid >> 6, l = tid & 63;
  const int lrow = l & 15, lk = l >> 4;
  const int nwg = gridDim.x * gridDim.y;
  int lin = blockIdx.y * gridDim.x + blockIdx.x;
  lin = (lin & 7) * (nwg >> 3) + (lin >> 3);
  const int m0 = (lin / gridDim.x) * 128, n0 = (lin % gridDim.x) * 128;
  const int wm = w >> 1, wn = w & 1;

  const int r0 = tid >> 2;
  const int sl = tid & 3;
  const int ls0 = sl ^ ((r0 >> 1) & 3);
  const int r1 = r0 + 64;
  const int ls1 = sl ^ ((r1 >> 1) & 3);
  const bf16_t* gA0 = A + (size_t)(m0 + r0) * lda + ls0 * 8;
  const bf16_t* gA1 = A + (size_t)(m0 + r1) * lda + ls1 * 8;
  const bf16_t* gB0 = Bm + (size_t)(n0 + r0) * ldb + ls0 * 8;
  const bf16_t* gB1 = Bm + (size_t)(n0 + r1) * ldb + ls1 * 8;
  const int lofs = tid * 8;

  f32x4 acc[4][4] = {};
  const int nkt = K >> 5;

  gload16(gA0, &lsA[0][lofs]);
  gload16(gA1, &lsA[0][lofs + 2048]);
  gload16(gB0, &lsB[0][lofs]);
  gload16(gB1, &lsB[0][lofs + 2048]);
  __syncthreads();

  for (int kt = 0; kt < nkt; ++kt) {
    const int buf = kt & 1;
    if (kt + 1 < nkt) {
      const int ko = (kt + 1) << 5;
      gload16(gA0 + ko, &lsA[buf ^ 1][lofs]);
      gload16(gA1 + ko, &lsA[buf ^ 1][lofs + 2048]);
      gload16(gB0 + ko, &lsB[buf ^ 1][lofs]);
      gload16(gB1 + ko, &lsB[buf ^ 1][lofs + 2048]);
    }
    bf16x8 af[4], bfv[4];
#pragma unroll
    for (int mi = 0; mi < 4; ++mi) {
      const int r = wm * 64 + mi * 16 + lrow;
      const int ps = lk ^ ((r >> 1) & 3);
      af[mi] = *reinterpret_cast<const bf16x8*>(&lsA[buf][r * 32 + ps * 8]);
    }
#pragma unroll
    for (int ni = 0; ni < 4; ++ni) {
      const int r = wn * 64 + ni * 16 + lrow;
      const int ps = lk ^ ((r >> 1) & 3);
      bfv[ni] = *reinterpret_cast<const bf16x8*>(&lsB[buf][r * 32 + ps * 8]);
    }
#pragma unroll
    for (int mi = 0; mi < 4; ++mi)
#pragma unroll
      for (int ni = 0; ni < 4; ++ni)
        acc[mi][ni] = MFMA16(af[mi], bfv[ni], acc[mi][ni]);
    __syncthreads();
  }

  // C/D layout: col = lane&15, row = (lane>>4)*4 + reg
#pragma unroll
  for (int mi = 0; mi < 4; ++mi) {
    const int row = m0 + wm * 64 + mi * 16 + lk * 4;
#pragma unroll
    for (int ni = 0; ni < 4; ++ni) {
      const int col = n0 + wn * 64 + ni * 16 + lrow;
#pragma unroll
      for (int rg = 0; rg < 4; ++rg)
        C[(size_t)(row + rg) * N + col] = acc[mi][ni][rg];
    }
  }
}

// ---------------------------------------------------------------------------
// QKV epilogue.  qkv raw = [4096][3072] f32 (q | k | v).  RMS-norm(q,k) +
// partial RoPE in fp32; q gets gain*(1/sqrt(128))*log2(e) folded in, stored
// hi/lo bf16 [.][256]; k plain bf16 [.][128]; v += ve_embed, plain bf16.
// ---------------------------------------------------------------------------
__global__ __launch_bounds__(256) void k_qkv_epi(
    const float* __restrict__ qkv, const float* __restrict__ ve,
    const float* __restrict__ qgain,
    const float* __restrict__ ctab, const float* __restrict__ stab,
    bf16_t* __restrict__ qn2, bf16_t* __restrict__ kn, bf16_t* __restrict__ vn)
{
  const int blk = blockIdx.x;           // b*2048 + t
  const int b = blk >> 11, t = blk & 2047;
  const int w = threadIdx.x >> 6, l = threadIdx.x & 63;
  const int i32 = l & 31;
  const float c = ctab[t * 32 + i32], s = stab[t * 32 + i32];
  const float EPS = 1.1920929e-07f;
  constexpr float SCALE_L2E = 0.088388347648318447f * 1.4426950408889634f;

  // Q: wave w handles heads w, w+4, w+8, w+12
#pragma unroll
  for (int it = 0; it < 4; ++it) {
    const int h = w + it * 4;
    const float* row = qkv + (size_t)blk * 3072 + h * 128;
    float x0 = row[l], x1 = row[l + 64];
    float ss = x0 * x0 + x1 * x1;
#pragma unroll
    for (int off = 32; off; off >>= 1) ss += __shfl_xor(ss, off);
    const float rn = rsqrtf(ss * (1.0f / 128.0f) + EPS);
    x0 *= rn; x1 *= rn;
    const float p = __shfl_xor(x0, 32);
    float xr = (l < 32) ? (x0 * c - p * s) : (p * s + x0 * c);
    const float g = qgain[h] * SCALE_L2E;
    xr *= g; x1 *= g;
    bf16_t* orow = qn2 + (((size_t)(b * 16 + h)) * 2048 + t) * 256;
    const bf16_t h0 = to_bf16(xr), h1 = to_bf16(x1);
    orow[l] = h0;        orow[128 + l] = to_bf16(xr - (float)h0);
    orow[l + 64] = h1;   orow[192 + l] = to_bf16(x1 - (float)h1);
  }
  // K: wave w -> kv head w (plain bf16)
  {
    const float* row = qkv + (size_t)blk * 3072 + 2048 + w * 128;
    float x0 = row[l], x1 = row[l + 64];
    float ss = x0 * x0 + x1 * x1;
#pragma unroll
    for (int off = 32; off; off >>= 1) ss += __shfl_xor(ss, off);
    const float rn = rsqrtf(ss * (1.0f / 128.0f) + EPS);
    x0 *= rn; x1 *= rn;
    const float p = __shfl_xor(x0, 32);
    const float xr = (l < 32) ? (x0 * c - p * s) : (p * s + x0 * c);
    bf16_t* orow = kn + (((size_t)(b * 4 + w)) * 2048 + t) * 128;
    orow[l] = to_bf16(xr);
    orow[l + 64] = to_bf16(x1);
  }
  // V: wave w -> kv head w ; v = vraw + ve
  {
    const float* row = qkv + (size_t)blk * 3072 + 2560 + w * 128;
    const float* verow = ve + (size_t)blk * 512 + w * 128;
    bf16_t* orow = vn + (((size_t)(b * 4 + w)) * 2048 + t) * 128;
    orow[l] = to_bf16(row[l] + verow[l]);
    orow[l + 64] = to_bf16(row[l + 64] + verow[l + 64]);
  }
}

// ---------------------------------------------------------------------------
// Causal GQA flash attention.  q hi/lo (2-term S), k plain.  QBLK=64 (4 waves
// x 16 q-rows), KVBLK=64, longest-qt-first.
// LDS: lsK [64][136] padded (2-way reads), lsV^T [128][72] XOR-swizzled,
// lsP per-wave [16][72].  45KB -> 3 blocks/CU.  2 barriers/tile.  K+V
// prefetched into registers one tile ahead.
// ---------------------------------------------------------------------------
__global__ __launch_bounds__(256, 3) void k_attn(
    const bf16_t* __restrict__ qn2, const bf16_t* __restrict__ kn,
    const bf16_t* __restrict__ vn, bf16_t* __restrict__ y)
{
  __shared__ __align__(16) bf16_t lsK[64 * 136];      // 17408 B
  __shared__ __align__(16) bf16_t lsV[128 * 72];      // 18432 B
  __shared__ __align__(16) bf16_t lsPb[4][16 * 72];   //  9216 B
  const int qt = 31 - (int)blockIdx.y;  // longest first
  const int bh = blockIdx.x;            // 0..31
  const int b = bh >> 4, h = bh & 15, kvh = h >> 2;
  const int tid = threadIdx.x, w = tid >> 6, l = tid & 63;
  const int lrow = l & 15, lk = l >> 4;
  const int qbase = qt * 64 + w * 16;
  constexpr float NEG = -1e30f;
  bf16_t* lsP = lsPb[w];

  // Q fragments (A-frag: row = lane&15, k = lk*8+j), hi and lo
  const bf16_t* qp = qn2 + ((size_t)(b * 16 + h) * 2048) * 256;
  bf16x8 aQh[4], aQl[4];
#pragma unroll
  for (int kf = 0; kf < 4; ++kf) {
    const size_t base = (size_t)(qbase + lrow) * 256 + kf * 32 + lk * 8;
    aQh[kf] = *reinterpret_cast<const bf16x8*>(qp + base);
    aQl[kf] = *reinterpret_cast<const bf16x8*>(qp + base + 128);
  }

  const bf16_t* kp = kn + ((size_t)(b * 4 + kvh) * 2048) * 128;
  const bf16_t* vp = vn + ((size_t)(b * 4 + kvh) * 2048) * 128;

  f32x4 o[8] = {};
  float mst[4], lst[4];
#pragma unroll
  for (int rg = 0; rg < 4; ++rg) { mst[rg] = NEG; lst[rg] = 0.f; }

  // K/V register prefetch (tile t0): chunk cch = tid + it*256,
  // row = cch>>4 (0..63), slot = cch&15.
  bf16x8 kreg[4], vreg[4];
  auto loadKV = [&](int t0) {
#pragma unroll
    for (int it = 0; it < 4; ++it) {
      const int cch = tid + it * 256;
      const size_t goff = (size_t)(t0 + (cch >> 4)) * 128 + (cch & 15) * 8;
      kreg[it] = *reinterpret_cast<const bf16x8*>(kp + goff);
      vreg[it] = *reinterpret_cast<const bf16x8*>(vp + goff);
    }
  };
  loadKV(0);

  const int ntiles = qt + 1;
  for (int tt = 0; tt < ntiles; ++tt) {
    __syncthreads();  // prior tile's K/V LDS reads done before restage
    // stage K [64][136] + V^T [128][72] (col' = kv ^ ((dg&7)<<3)) from regs
#pragma unroll
    for (int it = 0; it < 4; ++it) {
      const int cch = tid + it * 256;
      const int r = cch >> 4, dg = cch & 15;
      *reinterpret_cast<bf16x8*>(&lsK[r * 136 + dg * 8]) = kreg[it];
      const int colb = r ^ ((dg & 7) << 3);
#pragma unroll
      for (int j = 0; j < 8; ++j) lsV[(dg * 8 + j) * 72 + colb] = vreg[it][j];
    }
    // prefetch next tile's K/V (in flight across S + softmax + PV)
    if (tt + 1 < ntiles) loadKV((tt + 1) * 64);
    __syncthreads();  // staged data visible

    // S = Qh*Kh + Ql*Kh  (16 q-rows x 64 kv)
    f32x4 sacc[4] = {};
#pragma unroll
    for (int cf = 0; cf < 4; ++cf) {
      const int krow = cf * 16 + lrow;
#pragma unroll
      for (int kf = 0; kf < 4; ++kf) {
        const bf16x8 bK = *reinterpret_cast<const bf16x8*>(
            &lsK[krow * 136 + kf * 32 + lk * 8]);
        sacc[cf] = MFMA16(aQh[kf], bK, sacc[cf]);
        sacc[cf] = MFMA16(aQl[kf], bK, sacc[cf]);
      }
    }

    // online softmax, log2 domain; mask only on diagonal tile
    if (tt == qt) {
#pragma unroll
      for (int rg = 0; rg < 4; ++rg) {
        const int qi = w * 16 + lk * 4 + rg;  // within-tile row
#pragma unroll
        for (int cf = 0; cf < 4; ++cf)
          if (cf * 16 + lrow > qi) sacc[cf][rg] = NEG;
      }
    }
    float pmax[4];
#pragma unroll
    for (int rg = 0; rg < 4; ++rg) {
      float mx = fmaxf(fmaxf(sacc[0][rg], sacc[1][rg]),
                       fmaxf(sacc[2][rg], sacc[3][rg]));
      mx = fmaxf(mx, __shfl_xor(mx, 1));
      mx = fmaxf(mx, __shfl_xor(mx, 2));
      mx = fmaxf(mx, __shfl_xor(mx, 4));
      mx = fmaxf(mx, __shfl_xor(mx, 8));
      pmax[rg] = mx;
    }
    const bool grow = (pmax[0] > mst[0] + 8.f) | (pmax[1] > mst[1] + 8.f) |
                      (pmax[2] > mst[2] + 8.f) | (pmax[3] > mst[3] + 8.f);
    if (__any(grow)) {
#pragma unroll
      for (int rg = 0; rg < 4; ++rg) {
        const float mnew = fmaxf(mst[rg], pmax[rg]);
        const float alpha = exp2f(mst[rg] - mnew);
        mst[rg] = mnew;
        lst[rg] *= alpha;
#pragma unroll
        for (int df = 0; df < 8; ++df) o[df][rg] *= alpha;
      }
    }
#pragma unroll
    for (int rg = 0; rg < 4; ++rg) {
      float rsum = 0.f;
#pragma unroll
      for (int cf = 0; cf < 4; ++cf) {
        const float p = exp2f(sacc[cf][rg] - mst[rg]);
        sacc[cf][rg] = p;
        rsum += p;
      }
      rsum += __shfl_xor(rsum, 1);
      rsum += __shfl_xor(rsum, 2);
      rsum += __shfl_xor(rsum, 4);
      rsum += __shfl_xor(rsum, 8);
      lst[rg] += rsum;
    }

    // P -> per-wave LDS (A-frag layout [16][72]); same-wave write->read
#pragma unroll
    for (int cf = 0; cf < 4; ++cf)
#pragma unroll
      for (int rg = 0; rg < 4; ++rg)
        lsP[(lk * 4 + rg) * 72 + cf * 16 + lrow] = to_bf16(sacc[cf][rg]);
    // PV
#pragma unroll
    for (int k2 = 0; k2 < 2; ++k2) {
      const bf16x8 aP = *reinterpret_cast<const bf16x8*>(
          &lsP[lrow * 72 + k2 * 32 + lk * 8]);
#pragma unroll
      for (int df = 0; df < 8; ++df) {
        const int row = df * 16 + lrow;
        const int colb = (k2 * 32 + lk * 8) ^ (((row >> 3) & 7) << 3);
        const bf16x8 bV = *reinterpret_cast<const bf16x8*>(&lsV[row * 72 + colb]);
        o[df] = MFMA16(aP, bV, o[df]);
      }
    }
  }

  // normalize + write y [b][t][h*128+d]
#pragma unroll
  for (int rg = 0; rg < 4; ++rg) {
    const float inv = 1.0f / lst[rg];
    const int qi = qbase + lk * 4 + rg;
    const size_t rowoff = ((size_t)(b * 2048 + qi)) * 2048 + h * 128;
#pragma unroll
    for (int df = 0; df < 8; ++df)
      y[rowoff + df * 16 + lrow] = to_bf16(o[df][rg] * inv);
  }
}

// ---------------------------------------------------------------------------
extern "C" void kernel_launch(void* const* d_in, const int* in_sizes, int n_in,
                              void* d_out, int out_size, void* d_ws, size_t ws_size,
                              hipStream_t stream) {
  const float* x  = (const float*)d_in[0];
  const float* ve = (const float*)d_in[1];
  const float* Wq = (const float*)d_in[2];
  const float* Wk = (const float*)d_in[3];
  const float* Wv = (const float*)d_in[4];
  const float* Wp = (const float*)d_in[5];
  const float* qg = (const float*)d_in[6];
  float* out = (float*)d_out;

  char* ws = (char*)d_ws;
  size_t off = 0;
  auto alloc = [&](size_t bytes) -> char* {
    char* p = ws + off;
    off += (bytes + 255) & ~(size_t)255;
    return p;
  };

  bf16_t* x3     = (bf16_t*)alloc((size_t)4096 * 6144 * 2);  // [xh|xl|xh]; later qn2
  bf16_t* wqkv3  = (bf16_t*)alloc((size_t)3072 * 6144 * 2);  // rows: Wq|Wk|Wv, [Wh|Wh|Wl]
  bf16_t* wpb    = (bf16_t*)alloc((size_t)2048 * 2048 * 2);
  float*  qkvraw = (float*)alloc((size_t)4096 * 3072 * 4);   // later yb
  bf16_t* kn     = (bf16_t*)alloc((size_t)2 * 4 * 2048 * 128 * 2);
  bf16_t* vn     = (bf16_t*)alloc((size_t)2 * 4 * 2048 * 128 * 2);
  float*  ctab   = (float*)alloc((size_t)2048 * 32 * 4);
  float*  stab   = (float*)alloc((size_t)2048 * 32 * 4);
  bf16_t* qn2    = x3;               // x3 dead after QKV GEMM
  bf16_t* yb     = (bf16_t*)qkvraw;  // qkvraw dead after epilogue
  (void)ws_size; (void)in_sizes; (void)n_in; (void)out_size;

  k_split_x<<<2048, 256, 0, stream>>>(x, x3);
  k_split_w<<<1024, 256, 0, stream>>>(Wq, wqkv3, (long)2048 * 2048);
  k_split_w<<<512,  256, 0, stream>>>(Wk, wqkv3 + (size_t)2048 * 6144, (long)512 * 2048);
  k_split_w<<<512,  256, 0, stream>>>(Wv, wqkv3 + (size_t)2560 * 6144, (long)512 * 2048);
  k_cast_bf16<<<1024, 256, 0, stream>>>(Wp, wpb, (long)2048 * 2048);
  k_rope_tab<<<256, 256, 0, stream>>>(ctab, stab);

  // qkvraw = [xh|xl|xh]·[Wh|Wh|Wl]^T  (single pass, M=4096 N=3072 K=6144)
  k_gemm_bt<<<dim3(24, 32), 256, 0, stream>>>(x3, wqkv3, qkvraw, 4096, 3072, 6144, 6144, 6144);

  k_qkv_epi<<<4096, 256, 0, stream>>>(qkvraw, ve, qg, ctab, stab, qn2, kn, vn);

  k_attn<<<dim3(32, 32), 256, 0, stream>>>(qn2, kn, vn, yb);

  k_gemm_bt<<<dim3(16, 32), 256, 0, stream>>>(yb, wpb, out, 4096, 2048, 2048, 2048, 2048);
}

// Round 6
// 361.058 us; speedup vs baseline: 1.5975x; 1.0492x over previous
//
#include <hip/hip_runtime.h>
#include <hip/hip_bf16.h>
#include <cstdint>
#include <cstddef>

// ---------------------------------------------------------------------------
// CausalSelfAttention fused block, MI355X/gfx950.  Round 6:
//  - NEW: 256x256/BK=64 8-phase GEMM (quadrant phases, counted vmcnt(4),
//    raw s_barrier, setprio) for the QKV projection (K=6144).
//  - proj GEMM stays on the proven 128^2 kernel; attn unchanged from R5.
// B=2 T=2048 D=2048 NH=16 NKV=4 HD=128 ROPE=64.
// ---------------------------------------------------------------------------

typedef __bf16 bf16_t;
typedef bf16_t bf16x8 __attribute__((ext_vector_type(8)));
typedef float f32x4 __attribute__((ext_vector_type(4)));

#define MFMA16(a, b, c) __builtin_amdgcn_mfma_f32_16x16x32_bf16((a), (b), (c), 0, 0, 0)
#define SBAR()   __builtin_amdgcn_s_barrier()
#define SCHED0() __builtin_amdgcn_sched_barrier(0)
#define LGKM0()  asm volatile("s_waitcnt lgkmcnt(0)" ::: "memory")
#define VMC(n)   asm volatile("s_waitcnt vmcnt(" #n ")" ::: "memory")

__device__ __forceinline__ bf16_t to_bf16(float f) {
  __hip_bfloat16 h = __float2bfloat16(f);
  return *reinterpret_cast<bf16_t*>(&h);
}

__device__ __forceinline__ void gload16(const bf16_t* g, bf16_t* l) {
  auto lds_ptr = reinterpret_cast<__attribute__((address_space(3))) unsigned int*>(
      reinterpret_cast<uintptr_t>(l));
  auto g_ptr = reinterpret_cast<const __attribute__((address_space(1))) unsigned int*>(
      reinterpret_cast<uintptr_t>(g));
  __builtin_amdgcn_global_load_lds(g_ptr, lds_ptr, 16, 0, 0);
}

// ---------------------------------------------------------------------------
// fp32 -> bf16 cast, vectorized
// ---------------------------------------------------------------------------
__global__ void k_cast_bf16(const float* __restrict__ in, bf16_t* __restrict__ o, long n) {
  long i = ((long)blockIdx.x * blockDim.x + threadIdx.x) * 4;
  const long step = (long)gridDim.x * blockDim.x * 4;
  for (; i < n; i += step) {
    const float4 v = *reinterpret_cast<const float4*>(in + i);
    bf16_t r[4] = {to_bf16(v.x), to_bf16(v.y), to_bf16(v.z), to_bf16(v.w)};
    *reinterpret_cast<uint64_t*>(o + i) = *reinterpret_cast<const uint64_t*>(r);
  }
}

// ---------------------------------------------------------------------------
// x split: in [4096][2048] fp32 -> x3 [4096][6144] bf16 = [xh | xl | xh]
// ---------------------------------------------------------------------------
__global__ void k_split_x(const float* __restrict__ in, bf16_t* __restrict__ x3) {
  long i = ((long)blockIdx.x * blockDim.x + threadIdx.x) * 4;
  const long step = (long)gridDim.x * blockDim.x * 4;
  for (; i < (long)4096 * 2048; i += step) {
    const float4 v = *reinterpret_cast<const float4*>(in + i);
    const long row = i >> 11, col = i & 2047;
    bf16_t h[4], l[4];
    const float vv[4] = {v.x, v.y, v.z, v.w};
#pragma unroll
    for (int j = 0; j < 4; ++j) {
      h[j] = to_bf16(vv[j]);
      l[j] = to_bf16(vv[j] - (float)h[j]);
    }
    const uint64_t h64 = *reinterpret_cast<const uint64_t*>(h);
    bf16_t* rp = x3 + row * 6144;
    *reinterpret_cast<uint64_t*>(rp + col) = h64;
    *reinterpret_cast<uint64_t*>(rp + 2048 + col) = *reinterpret_cast<const uint64_t*>(l);
    *reinterpret_cast<uint64_t*>(rp + 4096 + col) = h64;
  }
}

// ---------------------------------------------------------------------------
// W split: W [R][2048] fp32 -> w3 [R][6144] = [Wh | Wh | Wl]
// ---------------------------------------------------------------------------
__global__ void k_split_w(const float* __restrict__ W, bf16_t* __restrict__ w3, long n) {
  long i = ((long)blockIdx.x * blockDim.x + threadIdx.x) * 4;
  const long step = (long)gridDim.x * blockDim.x * 4;
  for (; i < n; i += step) {
    const float4 v = *reinterpret_cast<const float4*>(W + i);
    const long row = i >> 11, col = i & 2047;
    bf16_t h[4], l[4];
    const float vv[4] = {v.x, v.y, v.z, v.w};
#pragma unroll
    for (int j = 0; j < 4; ++j) {
      h[j] = to_bf16(vv[j]);
      l[j] = to_bf16(vv[j] - (float)h[j]);
    }
    const uint64_t h64 = *reinterpret_cast<const uint64_t*>(h);
    bf16_t* rp = w3 + row * 6144;
    *reinterpret_cast<uint64_t*>(rp + col) = h64;
    *reinterpret_cast<uint64_t*>(rp + 2048 + col) = h64;
    *reinterpret_cast<uint64_t*>(rp + 4096 + col) = *reinterpret_cast<const uint64_t*>(l);
  }
}

// ---------------------------------------------------------------------------
// RoPE cos/sin table: [T=2048][32]
// ---------------------------------------------------------------------------
__global__ void k_rope_tab(float* __restrict__ ctab, float* __restrict__ stab) {
  const int idx = blockIdx.x * blockDim.x + threadIdx.x;
  if (idx >= 2048 * 32) return;
  const int t = idx >> 5, i = idx & 31;
  const float freq = exp2f(-(float)i * 0.2076205059304601f);  // 10000^(-i/64)
  const float f = (float)t * freq;
  ctab[idx] = cosf(f);
  stab[idx] = sinf(f);
}

// ---------------------------------------------------------------------------
// 256x256 8-phase NT GEMM (QKV): C[m,n] = sum_k A[m,k]*B[n,k], fp32 out.
// 512 threads = 8 waves (2M x 4N); BK=64; LDS 128KB = 2 bufs x {A0,A1,B0,B1}
// halves of 128rows x 64cols, slot-XOR swizzled (slot ^= row&7), staged via
// global_load_lds 16B.  Phases = C-quadrants (mh,nh); per phase one half-tile
// stage; single s_waitcnt vmcnt(4) per K-tile (tile t+1 fully landed, 2
// halves of t+2 in flight).  Requires M%256==0, N%256==0, K%64==0, nkt>=2,
// grid (N/256, M/256), nwg%8==0.
// ---------------------------------------------------------------------------
__global__ __launch_bounds__(512, 2) void k_gemm256(
    const bf16_t* __restrict__ A, const bf16_t* __restrict__ Bm,
    float* __restrict__ C, int M, int N, int K, int lda, int ldb)
{
  __shared__ __align__(16) bf16_t lds[2][4][8192];  // [buf][A0,A1,B0,B1][16KB]
  const int tid = threadIdx.x;
  const int l = tid & 63, w = tid >> 6;
  const int lrow = l & 15, lk = l >> 4;
  const int wm = w >> 2, wn = w & 3;

  const int nwg = gridDim.x * gridDim.y;
  int lin = blockIdx.y * gridDim.x + blockIdx.x;
  lin = (lin & 7) * (nwg >> 3) + (lin >> 3);
  const int m0 = (lin / gridDim.x) * 256, n0 = (lin % gridDim.x) * 256;

  // staging geometry: thread -> (row = i*64 + tid>>3, slot = tid&7);
  // source column slice = (slot ^ (row&7))*8   (row&7 == (tid>>3)&7)
  const int srow = tid >> 3;
  const int scol = ((tid & 7) ^ (srow & 7)) << 3;
  const bf16_t* gA[2][2];  // [half][issue]
  const bf16_t* gB[2][2];
#pragma unroll
  for (int h = 0; h < 2; ++h)
#pragma unroll
    for (int i = 0; i < 2; ++i) {
      const int r = h * 128 + i * 64 + srow;
      gA[h][i] = A + (size_t)(m0 + r) * lda + scol;
      gB[h][i] = Bm + (size_t)(n0 + r) * ldb + scol;
    }

  auto stage = [&](int buf, int mtx, int h, int k0) {
    bf16_t* dst = &lds[buf][mtx * 2 + h][tid * 8];
    const bf16_t* s0 = (mtx == 0 ? gA[h][0] : gB[h][0]) + k0;
    const bf16_t* s1 = (mtx == 0 ? gA[h][1] : gB[h][1]) + k0;
    gload16(s0, dst);
    gload16(s1, dst + 4096);
  };
  auto rdA = [&](int buf, int mh, int mf, int ks) -> bf16x8 {
    const int row = wm * 64 + mf * 16 + lrow;
    const int slot = ((ks << 2) | lk) ^ (lrow & 7);
    return *reinterpret_cast<const bf16x8*>(&lds[buf][mh][row * 64 + slot * 8]);
  };
  auto rdB = [&](int buf, int nh, int nf, int ks) -> bf16x8 {
    const int row = wn * 32 + nf * 16 + lrow;
    const int slot = ((ks << 2) | lk) ^ (lrow & 7);
    return *reinterpret_cast<const bf16x8*>(&lds[buf][2 + nh][row * 64 + slot * 8]);
  };

  f32x4 acc[8][4] = {};   // [mh*4+mf][nh*2+nf]
  const int nkt = K >> 6;

  // prologue: tile0 all 4 halves + A0,B0 of tile1 -> vmcnt(4) leaves those 2 in flight
  stage(0, 0, 0, 0); stage(0, 0, 1, 0); stage(0, 1, 0, 0); stage(0, 1, 1, 0);
  const int k1p = (nkt > 1 ? 64 : 0);
  stage(1, 0, 0, k1p); stage(1, 1, 0, k1p);
  VMC(4); SCHED0();
  SBAR(); SCHED0();

  bf16x8 aA[4][2], bB0[2][2], bB1[2][2];
  for (int kt = 0; kt < nkt; ++kt) {
    const int b = kt & 1;
    const int kn1 = (kt + 1 < nkt ? kt + 1 : nkt - 1) << 6;
    const int kn2 = (kt + 2 < nkt ? kt + 2 : nkt - 1) << 6;

    // ---- phase 1: quad (mh0,nh0); stage A1(t+1)
    stage(b ^ 1, 0, 1, kn1);
#pragma unroll
    for (int mf = 0; mf < 4; ++mf) { aA[mf][0] = rdA(b, 0, mf, 0); aA[mf][1] = rdA(b, 0, mf, 1); }
#pragma unroll
    for (int nf = 0; nf < 2; ++nf) { bB0[nf][0] = rdB(b, 0, nf, 0); bB0[nf][1] = rdB(b, 0, nf, 1); }
    SBAR(); SCHED0(); LGKM0(); SCHED0();
    __builtin_amdgcn_s_setprio(1);
#pragma unroll
    for (int mf = 0; mf < 4; ++mf)
#pragma unroll
      for (int nf = 0; nf < 2; ++nf)
#pragma unroll
        for (int ks = 0; ks < 2; ++ks)
          acc[mf][nf] = MFMA16(aA[mf][ks], bB0[nf][ks], acc[mf][nf]);
    __builtin_amdgcn_s_setprio(0);
    SBAR(); SCHED0();

    // ---- phase 2: quad (mh0,nh1); stage B1(t+1)
    stage(b ^ 1, 1, 1, kn1);
#pragma unroll
    for (int nf = 0; nf < 2; ++nf) { bB1[nf][0] = rdB(b, 1, nf, 0); bB1[nf][1] = rdB(b, 1, nf, 1); }
    SBAR(); SCHED0(); LGKM0(); SCHED0();
    __builtin_amdgcn_s_setprio(1);
#pragma unroll
    for (int mf = 0; mf < 4; ++mf)
#pragma unroll
      for (int nf = 0; nf < 2; ++nf)
#pragma unroll
        for (int ks = 0; ks < 2; ++ks)
          acc[mf][2 + nf] = MFMA16(aA[mf][ks], bB1[nf][ks], acc[mf][2 + nf]);
    __builtin_amdgcn_s_setprio(0);
    SBAR(); SCHED0();

    // ---- phase 3: quad (mh1,nh0); stage A0(t+2) over dead A0(t)
    stage(b, 0, 0, kn2);
#pragma unroll
    for (int mf = 0; mf < 4; ++mf) { aA[mf][0] = rdA(b, 1, mf, 0); aA[mf][1] = rdA(b, 1, mf, 1); }
    SBAR(); SCHED0(); LGKM0(); SCHED0();
    __builtin_amdgcn_s_setprio(1);
#pragma unroll
    for (int mf = 0; mf < 4; ++mf)
#pragma unroll
      for (int nf = 0; nf < 2; ++nf)
#pragma unroll
        for (int ks = 0; ks < 2; ++ks)
          acc[4 + mf][nf] = MFMA16(aA[mf][ks], bB0[nf][ks], acc[4 + mf][nf]);
    __builtin_amdgcn_s_setprio(0);
    SBAR(); SCHED0();

    // ---- phase 4: quad (mh1,nh1); stage B0(t+2) over dead B0(t); vmcnt(4)
    stage(b, 1, 0, kn2);
    VMC(4); SCHED0();
    SBAR(); SCHED0();
    __builtin_amdgcn_s_setprio(1);
#pragma unroll
    for (int mf = 0; mf < 4; ++mf)
#pragma unroll
      for (int nf = 0; nf < 2; ++nf)
#pragma unroll
        for (int ks = 0; ks < 2; ++ks)
          acc[4 + mf][2 + nf] = MFMA16(aA[mf][ks], bB1[nf][ks], acc[4 + mf][2 + nf]);
    __builtin_amdgcn_s_setprio(0);
    SBAR(); SCHED0();
  }

  // C-write: row = m0 + mh*128 + wm*64 + mf*16 + lk*4 + rg ; col = n0 + nh*128 + wn*32 + nf*16 + lrow
#pragma unroll
  for (int mi = 0; mi < 8; ++mi) {
    const int row = m0 + (mi >> 2) * 128 + wm * 64 + (mi & 3) * 16 + lk * 4;
#pragma unroll
    for (int ni = 0; ni < 4; ++ni) {
      const int col = n0 + (ni >> 1) * 128 + wn * 32 + (ni & 1) * 16 + lrow;
#pragma unroll
      for (int rg = 0; rg < 4; ++rg)
        C[(size_t)(row + rg) * N + col] = acc[mi][ni][rg];
    }
  }
  (void)M;
}

// ---------------------------------------------------------------------------
// 128x128 NT GEMM (proj): C[m,n] = sum_k A[m,k]*B[n,k].
// ---------------------------------------------------------------------------
__global__ __launch_bounds__(256, 2) void k_gemm_bt(
    const bf16_t* __restrict__ A, const bf16_t* __restrict__ Bm,
    float* __restrict__ C, int M, int N, int K, int lda, int ldb)
{
  __shared__ __align__(16) bf16_t lsA[2][128 * 32];
  __shared__ __align__(16) bf16_t lsB[2][128 * 32];
  const int tid = threadIdx.x;
  const int w = tid >> 6, l = tid & 63;
  const int lrow = l & 15, lk = l >> 4;
  const int nwg = gridDim.x * gridDim.y;
  int lin = blockIdx.y * gridDim.x + blockIdx.x;
  lin = (lin & 7) * (nwg >> 3) + (lin >> 3);
  const int m0 = (lin / gridDim.x) * 128, n0 = (lin % gridDim.x) * 128;
  const int wm = w >> 1, wn = w & 1;

  const int r0 = tid >> 2;
  const int sl = tid & 3;
  const int ls0 = sl ^ ((r0 >> 1) & 3);
  const int r1 = r0 + 64;
  const int ls1 = sl ^ ((r1 >> 1) & 3);
  const bf16_t* gA0 = A + (size_t)(m0 + r0) * lda + ls0 * 8;
  const bf16_t* gA1 = A + (size_t)(m0 + r1) * lda + ls1 * 8;
  const bf16_t* gB0 = Bm + (size_t)(n0 + r0) * ldb + ls0 * 8;
  const bf16_t* gB1 = Bm + (size_t)(n0 + r1) * ldb + ls1 * 8;
  const int lofs = tid * 8;

  f32x4 acc[4][4] = {};
  const int nkt = K >> 5;

  gload16(gA0, &lsA[0][lofs]);
  gload16(gA1, &lsA[0][lofs + 2048]);
  gload16(gB0, &lsB[0][lofs]);
  gload16(gB1, &lsB[0][lofs + 2048]);
  __syncthreads();

  for (int kt = 0; kt < nkt; ++kt) {
    const int buf = kt & 1;
    if (kt + 1 < nkt) {
      const int ko = (kt + 1) << 5;
      gload16(gA0 + ko, &lsA[buf ^ 1][lofs]);
      gload16(gA1 + ko, &lsA[buf ^ 1][lofs + 2048]);
      gload16(gB0 + ko, &lsB[buf ^ 1][lofs]);
      gload16(gB1 + ko, &lsB[buf ^ 1][lofs + 2048]);
    }
    bf16x8 af[4], bfv[4];
#pragma unroll
    for (int mi = 0; mi < 4; ++mi) {
      const int r = wm * 64 + mi * 16 + lrow;
      const int ps = lk ^ ((r >> 1) & 3);
      af[mi] = *reinterpret_cast<const bf16x8*>(&lsA[buf][r * 32 + ps * 8]);
    }
#pragma unroll
    for (int ni = 0; ni < 4; ++ni) {
      const int r = wn * 64 + ni * 16 + lrow;
      const int ps = lk ^ ((r >> 1) & 3);
      bfv[ni] = *reinterpret_cast<const bf16x8*>(&lsB[buf][r * 32 + ps * 8]);
    }
#pragma unroll
    for (int mi = 0; mi < 4; ++mi)
#pragma unroll
      for (int ni = 0; ni < 4; ++ni)
        acc[mi][ni] = MFMA16(af[mi], bfv[ni], acc[mi][ni]);
    __syncthreads();
  }

#pragma unroll
  for (int mi = 0; mi < 4; ++mi) {
    const int row = m0 + wm * 64 + mi * 16 + lk * 4;
#pragma unroll
    for (int ni = 0; ni < 4; ++ni) {
      const int col = n0 + wn * 64 + ni * 16 + lrow;
#pragma unroll
      for (int rg = 0; rg < 4; ++rg)
        C[(size_t)(row + rg) * N + col] = acc[mi][ni][rg];
    }
  }
}

// ---------------------------------------------------------------------------
// QKV epilogue.  qkv raw = [4096][3072] f32 (q | k | v).  RMS-norm(q,k) +
// partial RoPE in fp32; q gets gain*(1/sqrt(128))*log2(e) folded in, stored
// hi/lo bf16 [.][256]; k plain bf16 [.][128]; v += ve_embed, plain bf16.
// ---------------------------------------------------------------------------
__global__ __launch_bounds__(256) void k_qkv_epi(
    const float* __restrict__ qkv, const float* __restrict__ ve,
    const float* __restrict__ qgain,
    const float* __restrict__ ctab, const float* __restrict__ stab,
    bf16_t* __restrict__ qn2, bf16_t* __restrict__ kn, bf16_t* __restrict__ vn)
{
  const int blk = blockIdx.x;           // b*2048 + t
  const int b = blk >> 11, t = blk & 2047;
  const int w = threadIdx.x >> 6, l = threadIdx.x & 63;
  const int i32 = l & 31;
  const float c = ctab[t * 32 + i32], s = stab[t * 32 + i32];
  const float EPS = 1.1920929e-07f;
  constexpr float SCALE_L2E = 0.088388347648318447f * 1.4426950408889634f;

  // Q: wave w handles heads w, w+4, w+8, w+12
#pragma unroll
  for (int it = 0; it < 4; ++it) {
    const int h = w + it * 4;
    const float* row = qkv + (size_t)blk * 3072 + h * 128;
    float x0 = row[l], x1 = row[l + 64];
    float ss = x0 * x0 + x1 * x1;
#pragma unroll
    for (int off = 32; off; off >>= 1) ss += __shfl_xor(ss, off);
    const float rn = rsqrtf(ss * (1.0f / 128.0f) + EPS);
    x0 *= rn; x1 *= rn;
    const float p = __shfl_xor(x0, 32);
    float xr = (l < 32) ? (x0 * c - p * s) : (p * s + x0 * c);
    const float g = qgain[h] * SCALE_L2E;
    xr *= g; x1 *= g;
    bf16_t* orow = qn2 + (((size_t)(b * 16 + h)) * 2048 + t) * 256;
    const bf16_t h0 = to_bf16(xr), h1 = to_bf16(x1);
    orow[l] = h0;        orow[128 + l] = to_bf16(xr - (float)h0);
    orow[l + 64] = h1;   orow[192 + l] = to_bf16(x1 - (float)h1);
  }
  // K: wave w -> kv head w (plain bf16)
  {
    const float* row = qkv + (size_t)blk * 3072 + 2048 + w * 128;
    float x0 = row[l], x1 = row[l + 64];
    float ss = x0 * x0 + x1 * x1;
#pragma unroll
    for (int off = 32; off; off >>= 1) ss += __shfl_xor(ss, off);
    const float rn = rsqrtf(ss * (1.0f / 128.0f) + EPS);
    x0 *= rn; x1 *= rn;
    const float p = __shfl_xor(x0, 32);
    const float xr = (l < 32) ? (x0 * c - p * s) : (p * s + x0 * c);
    bf16_t* orow = kn + (((size_t)(b * 4 + w)) * 2048 + t) * 128;
    orow[l] = to_bf16(xr);
    orow[l + 64] = to_bf16(x1);
  }
  // V: wave w -> kv head w ; v = vraw + ve
  {
    const float* row = qkv + (size_t)blk * 3072 + 2560 + w * 128;
    const float* verow = ve + (size_t)blk * 512 + w * 128;
    bf16_t* orow = vn + (((size_t)(b * 4 + w)) * 2048 + t) * 128;
    orow[l] = to_bf16(row[l] + verow[l]);
    orow[l + 64] = to_bf16(row[l + 64] + verow[l + 64]);
  }
}

// ---------------------------------------------------------------------------
// Causal GQA flash attention (unchanged from R5).
// ---------------------------------------------------------------------------
__global__ __launch_bounds__(256, 3) void k_attn(
    const bf16_t* __restrict__ qn2, const bf16_t* __restrict__ kn,
    const bf16_t* __restrict__ vn, bf16_t* __restrict__ y)
{
  __shared__ __align__(16) bf16_t lsK[64 * 136];      // 17408 B
  __shared__ __align__(16) bf16_t lsV[128 * 72];      // 18432 B
  __shared__ __align__(16) bf16_t lsPb[4][16 * 72];   //  9216 B
  const int qt = 31 - (int)blockIdx.y;  // longest first
  const int bh = blockIdx.x;            // 0..31
  const int b = bh >> 4, h = bh & 15, kvh = h >> 2;
  const int tid = threadIdx.x, w = tid >> 6, l = tid & 63;
  const int lrow = l & 15, lk = l >> 4;
  const int qbase = qt * 64 + w * 16;
  constexpr float NEG = -1e30f;
  bf16_t* lsP = lsPb[w];

  const bf16_t* qp = qn2 + ((size_t)(b * 16 + h) * 2048) * 256;
  bf16x8 aQh[4], aQl[4];
#pragma unroll
  for (int kf = 0; kf < 4; ++kf) {
    const size_t base = (size_t)(qbase + lrow) * 256 + kf * 32 + lk * 8;
    aQh[kf] = *reinterpret_cast<const bf16x8*>(qp + base);
    aQl[kf] = *reinterpret_cast<const bf16x8*>(qp + base + 128);
  }

  const bf16_t* kp = kn + ((size_t)(b * 4 + kvh) * 2048) * 128;
  const bf16_t* vp = vn + ((size_t)(b * 4 + kvh) * 2048) * 128;

  f32x4 o[8] = {};
  float mst[4], lst[4];
#pragma unroll
  for (int rg = 0; rg < 4; ++rg) { mst[rg] = NEG; lst[rg] = 0.f; }

  bf16x8 kreg[4], vreg[4];
  auto loadKV = [&](int t0) {
#pragma unroll
    for (int it = 0; it < 4; ++it) {
      const int cch = tid + it * 256;
      const size_t goff = (size_t)(t0 + (cch >> 4)) * 128 + (cch & 15) * 8;
      kreg[it] = *reinterpret_cast<const bf16x8*>(kp + goff);
      vreg[it] = *reinterpret_cast<const bf16x8*>(vp + goff);
    }
  };
  loadKV(0);

  const int ntiles = qt + 1;
  for (int tt = 0; tt < ntiles; ++tt) {
    __syncthreads();
#pragma unroll
    for (int it = 0; it < 4; ++it) {
      const int cch = tid + it * 256;
      const int r = cch >> 4, dg = cch & 15;
      *reinterpret_cast<bf16x8*>(&lsK[r * 136 + dg * 8]) = kreg[it];
      const int colb = r ^ ((dg & 7) << 3);
#pragma unroll
      for (int j = 0; j < 8; ++j) lsV[(dg * 8 + j) * 72 + colb] = vreg[it][j];
    }
    if (tt + 1 < ntiles) loadKV((tt + 1) * 64);
    __syncthreads();

    f32x4 sacc[4] = {};
#pragma unroll
    for (int cf = 0; cf < 4; ++cf) {
      const int krow = cf * 16 + lrow;
#pragma unroll
      for (int kf = 0; kf < 4; ++kf) {
        const bf16x8 bK = *reinterpret_cast<const bf16x8*>(
            &lsK[krow * 136 + kf * 32 + lk * 8]);
        sacc[cf] = MFMA16(aQh[kf], bK, sacc[cf]);
        sacc[cf] = MFMA16(aQl[kf], bK, sacc[cf]);
      }
    }

    if (tt == qt) {
#pragma unroll
      for (int rg = 0; rg < 4; ++rg) {
        const int qi = w * 16 + lk * 4 + rg;
#pragma unroll
        for (int cf = 0; cf < 4; ++cf)
          if (cf * 16 + lrow > qi) sacc[cf][rg] = NEG;
      }
    }
    float pmax[4];
#pragma unroll
    for (int rg = 0; rg < 4; ++rg) {
      float mx = fmaxf(fmaxf(sacc[0][rg], sacc[1][rg]),
                       fmaxf(sacc[2][rg], sacc[3][rg]));
      mx = fmaxf(mx, __shfl_xor(mx, 1));
      mx = fmaxf(mx, __shfl_xor(mx, 2));
      mx = fmaxf(mx, __shfl_xor(mx, 4));
      mx = fmaxf(mx, __shfl_xor(mx, 8));
      pmax[rg] = mx;
    }
    const bool grow = (pmax[0] > mst[0] + 8.f) | (pmax[1] > mst[1] + 8.f) |
                      (pmax[2] > mst[2] + 8.f) | (pmax[3] > mst[3] + 8.f);
    if (__any(grow)) {
#pragma unroll
      for (int rg = 0; rg < 4; ++rg) {
        const float mnew = fmaxf(mst[rg], pmax[rg]);
        const float alpha = exp2f(mst[rg] - mnew);
        mst[rg] = mnew;
        lst[rg] *= alpha;
#pragma unroll
        for (int df = 0; df < 8; ++df) o[df][rg] *= alpha;
      }
    }
#pragma unroll
    for (int rg = 0; rg < 4; ++rg) {
      float rsum = 0.f;
#pragma unroll
      for (int cf = 0; cf < 4; ++cf) {
        const float p = exp2f(sacc[cf][rg] - mst[rg]);
        sacc[cf][rg] = p;
        rsum += p;
      }
      rsum += __shfl_xor(rsum, 1);
      rsum += __shfl_xor(rsum, 2);
      rsum += __shfl_xor(rsum, 4);
      rsum += __shfl_xor(rsum, 8);
      lst[rg] += rsum;
    }

#pragma unroll
    for (int cf = 0; cf < 4; ++cf)
#pragma unroll
      for (int rg = 0; rg < 4; ++rg)
        lsP[(lk * 4 + rg) * 72 + cf * 16 + lrow] = to_bf16(sacc[cf][rg]);
#pragma unroll
    for (int k2 = 0; k2 < 2; ++k2) {
      const bf16x8 aP = *reinterpret_cast<const bf16x8*>(
          &lsP[lrow * 72 + k2 * 32 + lk * 8]);
#pragma unroll
      for (int df = 0; df < 8; ++df) {
        const int row = df * 16 + lrow;
        const int colb = (k2 * 32 + lk * 8) ^ (((row >> 3) & 7) << 3);
        const bf16x8 bV = *reinterpret_cast<const bf16x8*>(&lsV[row * 72 + colb]);
        o[df] = MFMA16(aP, bV, o[df]);
      }
    }
  }

#pragma unroll
  for (int rg = 0; rg < 4; ++rg) {
    const float inv = 1.0f / lst[rg];
    const int qi = qbase + lk * 4 + rg;
    const size_t rowoff = ((size_t)(b * 2048 + qi)) * 2048 + h * 128;
#pragma unroll
    for (int df = 0; df < 8; ++df)
      y[rowoff + df * 16 + lrow] = to_bf16(o[df][rg] * inv);
  }
}

// ---------------------------------------------------------------------------
extern "C" void kernel_launch(void* const* d_in, const int* in_sizes, int n_in,
                              void* d_out, int out_size, void* d_ws, size_t ws_size,
                              hipStream_t stream) {
  const float* x  = (const float*)d_in[0];
  const float* ve = (const float*)d_in[1];
  const float* Wq = (const float*)d_in[2];
  const float* Wk = (const float*)d_in[3];
  const float* Wv = (const float*)d_in[4];
  const float* Wp = (const float*)d_in[5];
  const float* qg = (const float*)d_in[6];
  float* out = (float*)d_out;

  char* ws = (char*)d_ws;
  size_t off = 0;
  auto alloc = [&](size_t bytes) -> char* {
    char* p = ws + off;
    off += (bytes + 255) & ~(size_t)255;
    return p;
  };

  bf16_t* x3     = (bf16_t*)alloc((size_t)4096 * 6144 * 2);  // [xh|xl|xh]; later qn2
  bf16_t* wqkv3  = (bf16_t*)alloc((size_t)3072 * 6144 * 2);  // rows: Wq|Wk|Wv, [Wh|Wh|Wl]
  bf16_t* wpb    = (bf16_t*)alloc((size_t)2048 * 2048 * 2);
  float*  qkvraw = (float*)alloc((size_t)4096 * 3072 * 4);   // later yb
  bf16_t* kn     = (bf16_t*)alloc((size_t)2 * 4 * 2048 * 128 * 2);
  bf16_t* vn     = (bf16_t*)alloc((size_t)2 * 4 * 2048 * 128 * 2);
  float*  ctab   = (float*)alloc((size_t)2048 * 32 * 4);
  float*  stab   = (float*)alloc((size_t)2048 * 32 * 4);
  bf16_t* qn2    = x3;               // x3 dead after QKV GEMM
  bf16_t* yb     = (bf16_t*)qkvraw;  // qkvraw dead after epilogue
  (void)ws_size; (void)in_sizes; (void)n_in; (void)out_size;

  k_split_x<<<2048, 256, 0, stream>>>(x, x3);
  k_split_w<<<1024, 256, 0, stream>>>(Wq, wqkv3, (long)2048 * 2048);
  k_split_w<<<512,  256, 0, stream>>>(Wk, wqkv3 + (size_t)2048 * 6144, (long)512 * 2048);
  k_split_w<<<512,  256, 0, stream>>>(Wv, wqkv3 + (size_t)2560 * 6144, (long)512 * 2048);
  k_cast_bf16<<<1024, 256, 0, stream>>>(Wp, wpb, (long)2048 * 2048);
  k_rope_tab<<<256, 256, 0, stream>>>(ctab, stab);

  // qkvraw = [xh|xl|xh]·[Wh|Wh|Wl]^T  (M=4096 N=3072 K=6144, 8-phase 256²)
  k_gemm256<<<dim3(12, 16), 512, 0, stream>>>(x3, wqkv3, qkvraw, 4096, 3072, 6144, 6144, 6144);

  k_qkv_epi<<<4096, 256, 0, stream>>>(qkvraw, ve, qg, ctab, stab, qn2, kn, vn);

  k_attn<<<dim3(32, 32), 256, 0, stream>>>(qn2, kn, vn, yb);

  k_gemm_bt<<<dim3(16, 32), 256, 0, stream>>>(yb, wpb, out, 4096, 2048, 2048, 2048, 2048);
}

// Round 7
// 333.756 us; speedup vs baseline: 1.7282x; 1.0818x over previous
//
#include <hip/hip_runtime.h>
#include <hip/hip_bf16.h>
#include <cstdint>
#include <cstddef>

// ---------------------------------------------------------------------------
// CausalSelfAttention fused block, MI355X/gfx950.  Round 7:
//  - QKV GEMM: 256x192 tile (grid 16x16 = 256 blocks = 1/CU, 100% fill),
//    BK=64, 8 waves, 2-phase schedule (2 barriers/K-tile), counted vmcnt(7),
//    112KB LDS.  Proj stays on 128^2 kernel; attn unchanged from R5.
// B=2 T=2048 D=2048 NH=16 NKV=4 HD=128 ROPE=64.
// ---------------------------------------------------------------------------

typedef __bf16 bf16_t;
typedef bf16_t bf16x8 __attribute__((ext_vector_type(8)));
typedef float f32x4 __attribute__((ext_vector_type(4)));

#define MFMA16(a, b, c) __builtin_amdgcn_mfma_f32_16x16x32_bf16((a), (b), (c), 0, 0, 0)
#define SBAR()   __builtin_amdgcn_s_barrier()
#define SCHED0() __builtin_amdgcn_sched_barrier(0)
#define LGKM0()  asm volatile("s_waitcnt lgkmcnt(0)" ::: "memory")
#define VMC(n)   asm volatile("s_waitcnt vmcnt(" #n ")" ::: "memory")

__device__ __forceinline__ bf16_t to_bf16(float f) {
  __hip_bfloat16 h = __float2bfloat16(f);
  return *reinterpret_cast<bf16_t*>(&h);
}

__device__ __forceinline__ void gload16(const bf16_t* g, bf16_t* l) {
  auto lds_ptr = reinterpret_cast<__attribute__((address_space(3))) unsigned int*>(
      reinterpret_cast<uintptr_t>(l));
  auto g_ptr = reinterpret_cast<const __attribute__((address_space(1))) unsigned int*>(
      reinterpret_cast<uintptr_t>(g));
  __builtin_amdgcn_global_load_lds(g_ptr, lds_ptr, 16, 0, 0);
}

// ---------------------------------------------------------------------------
// fp32 -> bf16 cast, vectorized
// ---------------------------------------------------------------------------
__global__ void k_cast_bf16(const float* __restrict__ in, bf16_t* __restrict__ o, long n) {
  long i = ((long)blockIdx.x * blockDim.x + threadIdx.x) * 4;
  const long step = (long)gridDim.x * blockDim.x * 4;
  for (; i < n; i += step) {
    const float4 v = *reinterpret_cast<const float4*>(in + i);
    bf16_t r[4] = {to_bf16(v.x), to_bf16(v.y), to_bf16(v.z), to_bf16(v.w)};
    *reinterpret_cast<uint64_t*>(o + i) = *reinterpret_cast<const uint64_t*>(r);
  }
}

// ---------------------------------------------------------------------------
// x split: in [4096][2048] fp32 -> x3 [4096][6144] bf16 = [xh | xl | xh]
// ---------------------------------------------------------------------------
__global__ void k_split_x(const float* __restrict__ in, bf16_t* __restrict__ x3) {
  long i = ((long)blockIdx.x * blockDim.x + threadIdx.x) * 4;
  const long step = (long)gridDim.x * blockDim.x * 4;
  for (; i < (long)4096 * 2048; i += step) {
    const float4 v = *reinterpret_cast<const float4*>(in + i);
    const long row = i >> 11, col = i & 2047;
    bf16_t h[4], l[4];
    const float vv[4] = {v.x, v.y, v.z, v.w};
#pragma unroll
    for (int j = 0; j < 4; ++j) {
      h[j] = to_bf16(vv[j]);
      l[j] = to_bf16(vv[j] - (float)h[j]);
    }
    const uint64_t h64 = *reinterpret_cast<const uint64_t*>(h);
    bf16_t* rp = x3 + row * 6144;
    *reinterpret_cast<uint64_t*>(rp + col) = h64;
    *reinterpret_cast<uint64_t*>(rp + 2048 + col) = *reinterpret_cast<const uint64_t*>(l);
    *reinterpret_cast<uint64_t*>(rp + 4096 + col) = h64;
  }
}

// ---------------------------------------------------------------------------
// W split: W [R][2048] fp32 -> w3 [R][6144] = [Wh | Wh | Wl]
// ---------------------------------------------------------------------------
__global__ void k_split_w(const float* __restrict__ W, bf16_t* __restrict__ w3, long n) {
  long i = ((long)blockIdx.x * blockDim.x + threadIdx.x) * 4;
  const long step = (long)gridDim.x * blockDim.x * 4;
  for (; i < n; i += step) {
    const float4 v = *reinterpret_cast<const float4*>(W + i);
    const long row = i >> 11, col = i & 2047;
    bf16_t h[4], l[4];
    const float vv[4] = {v.x, v.y, v.z, v.w};
#pragma unroll
    for (int j = 0; j < 4; ++j) {
      h[j] = to_bf16(vv[j]);
      l[j] = to_bf16(vv[j] - (float)h[j]);
    }
    const uint64_t h64 = *reinterpret_cast<const uint64_t*>(h);
    bf16_t* rp = w3 + row * 6144;
    *reinterpret_cast<uint64_t*>(rp + col) = h64;
    *reinterpret_cast<uint64_t*>(rp + 2048 + col) = h64;
    *reinterpret_cast<uint64_t*>(rp + 4096 + col) = *reinterpret_cast<const uint64_t*>(l);
  }
}

// ---------------------------------------------------------------------------
// RoPE cos/sin table: [T=2048][32]
// ---------------------------------------------------------------------------
__global__ void k_rope_tab(float* __restrict__ ctab, float* __restrict__ stab) {
  const int idx = blockIdx.x * blockDim.x + threadIdx.x;
  if (idx >= 2048 * 32) return;
  const int t = idx >> 5, i = idx & 31;
  const float freq = exp2f(-(float)i * 0.2076205059304601f);  // 10000^(-i/64)
  const float f = (float)t * freq;
  ctab[idx] = cosf(f);
  stab[idx] = sinf(f);
}

// ---------------------------------------------------------------------------
// 256x192 NT GEMM (QKV): C[m,n] = sum_k A[m,k]*B[n,k], fp32 out.
// 512 threads = 8 waves (2M x 4N), wave-tile 128x48; BK=64.
// LDS 112KB = 2 bufs x {A 256x64 | B 192x64}, slot-XOR swizzle (slot ^= row&7),
// staged via global_load_lds 16B (7 units of 64rows x 64cols per buffer).
// 2-phase schedule: reads+MFMA(mh0) | lgkm0+SBAR | stage(t+2)+vmcnt(7)+
// MFMA(mh1, reg-only) | SBAR.  Requires M%256==0, N%192==0, K%64==0, nkt>=2,
// grid (N/192, M/256), nwg%8==0.
// ---------------------------------------------------------------------------
__global__ __launch_bounds__(512, 2) void k_gemmQ(
    const bf16_t* __restrict__ A, const bf16_t* __restrict__ Bm,
    float* __restrict__ C, int M, int N, int K, int lda, int ldb)
{
  __shared__ __align__(16) bf16_t lds[2][7 * 4096];  // [buf][A u0..3 | B u0..2]
  const int tid = threadIdx.x;
  const int l = tid & 63, w = tid >> 6;
  const int lrow = l & 15, lk = l >> 4;
  const int wm = w >> 2, wn = w & 3;

  const int nwg = gridDim.x * gridDim.y;
  int lin = blockIdx.y * gridDim.x + blockIdx.x;
  lin = (lin & 7) * (nwg >> 3) + (lin >> 3);
  const int m0 = (lin / gridDim.x) * 256, n0 = (lin % gridDim.x) * 192;

  // staging: thread -> (unit-row tid>>3, phys slot tid&7); src col = (slot ^ row&7)*8
  const int srow = tid >> 3;
  const int scol = ((tid & 7) ^ (srow & 7)) << 3;
  const bf16_t* gP[7];
#pragma unroll
  for (int u = 0; u < 4; ++u) gP[u] = A + (size_t)(m0 + u * 64 + srow) * lda + scol;
#pragma unroll
  for (int u = 0; u < 3; ++u) gP[4 + u] = Bm + (size_t)(n0 + u * 64 + srow) * ldb + scol;

  auto stageAll = [&](int buf, int k0) {
#pragma unroll
    for (int u = 0; u < 7; ++u) gload16(gP[u] + k0, &lds[buf][u * 4096 + tid * 8]);
  };
  auto rdA = [&](int buf, int mf, int ks) -> bf16x8 {
    const int row = wm * 128 + mf * 16 + lrow;            // 0..255
    const int slot = ((ks << 2) | lk) ^ (row & 7);
    return *reinterpret_cast<const bf16x8*>(&lds[buf][row * 64 + slot * 8]);
  };
  auto rdB = [&](int buf, int nf, int ks) -> bf16x8 {
    const int row = wn * 48 + nf * 16 + lrow;             // 0..191
    const int slot = ((ks << 2) | lk) ^ (row & 7);
    return *reinterpret_cast<const bf16x8*>(&lds[buf][16384 + row * 64 + slot * 8]);
  };

  f32x4 acc[8][3] = {};
  const int nkt = K >> 6;

  stageAll(0, 0);
  stageAll(1, nkt > 1 ? 64 : 0);
  VMC(7); SCHED0();
  SBAR(); SCHED0();

  bf16x8 aA[8][2], bB[3][2];
  for (int kt = 0; kt < nkt; ++kt) {
    const int b = kt & 1;
    const int kn2 = (kt + 2 < nkt ? kt + 2 : nkt - 1) << 6;

    // phase 1: read all frags of tile t, MFMA upper half (mh0)
#pragma unroll
    for (int mf = 0; mf < 8; ++mf) { aA[mf][0] = rdA(b, mf, 0); aA[mf][1] = rdA(b, mf, 1); }
#pragma unroll
    for (int nf = 0; nf < 3; ++nf) { bB[nf][0] = rdB(b, nf, 0); bB[nf][1] = rdB(b, nf, 1); }
    __builtin_amdgcn_s_setprio(1);
#pragma unroll
    for (int mf = 0; mf < 4; ++mf)
#pragma unroll
      for (int nf = 0; nf < 3; ++nf)
#pragma unroll
        for (int ks = 0; ks < 2; ++ks)
          acc[mf][nf] = MFMA16(aA[mf][ks], bB[nf][ks], acc[mf][nf]);
    __builtin_amdgcn_s_setprio(0);
    LGKM0(); SCHED0();       // all my ds_reads of buf b complete
    SBAR(); SCHED0();        // ... on every wave -> safe to overwrite buf b

    // phase 2: stage tile t+2 over dead buf b; wait tile t+1; MFMA lower half
    stageAll(b, kn2);
    VMC(7); SCHED0();        // t+1's 7 units landed (mine); SBAR below globalizes
    __builtin_amdgcn_s_setprio(1);
#pragma unroll
    for (int mf = 4; mf < 8; ++mf)
#pragma unroll
      for (int nf = 0; nf < 3; ++nf)
#pragma unroll
        for (int ks = 0; ks < 2; ++ks)
          acc[mf][nf] = MFMA16(aA[mf][ks], bB[nf][ks], acc[mf][nf]);
    __builtin_amdgcn_s_setprio(0);
    SBAR(); SCHED0();        // all waves past VMC -> t+1 resident for next reads
  }

  // C-write: row = m0 + wm*128 + mf*16 + lk*4 + rg ; col = n0 + wn*48 + nf*16 + lrow
#pragma unroll
  for (int mf = 0; mf < 8; ++mf) {
    const int row = m0 + wm * 128 + mf * 16 + lk * 4;
#pragma unroll
    for (int nf = 0; nf < 3; ++nf) {
      const int col = n0 + wn * 48 + nf * 16 + lrow;
#pragma unroll
      for (int rg = 0; rg < 4; ++rg)
        C[(size_t)(row + rg) * N + col] = acc[mf][nf][rg];
    }
  }
  (void)M;
}

// ---------------------------------------------------------------------------
// 128x128 NT GEMM (proj): C[m,n] = sum_k A[m,k]*B[n,k].
// ---------------------------------------------------------------------------
__global__ __launch_bounds__(256, 2) void k_gemm_bt(
    const bf16_t* __restrict__ A, const bf16_t* __restrict__ Bm,
    float* __restrict__ C, int M, int N, int K, int lda, int ldb)
{
  __shared__ __align__(16) bf16_t lsA[2][128 * 32];
  __shared__ __align__(16) bf16_t lsB[2][128 * 32];
  const int tid = threadIdx.x;
  const int w = tid >> 6, l = tid & 63;
  const int lrow = l & 15, lk = l >> 4;
  const int nwg = gridDim.x * gridDim.y;
  int lin = blockIdx.y * gridDim.x + blockIdx.x;
  lin = (lin & 7) * (nwg >> 3) + (lin >> 3);
  const int m0 = (lin / gridDim.x) * 128, n0 = (lin % gridDim.x) * 128;
  const int wm = w >> 1, wn = w & 1;

  const int r0 = tid >> 2;
  const int sl = tid & 3;
  const int ls0 = sl ^ ((r0 >> 1) & 3);
  const int r1 = r0 + 64;
  const int ls1 = sl ^ ((r1 >> 1) & 3);
  const bf16_t* gA0 = A + (size_t)(m0 + r0) * lda + ls0 * 8;
  const bf16_t* gA1 = A + (size_t)(m0 + r1) * lda + ls1 * 8;
  const bf16_t* gB0 = Bm + (size_t)(n0 + r0) * ldb + ls0 * 8;
  const bf16_t* gB1 = Bm + (size_t)(n0 + r1) * ldb + ls1 * 8;
  const int lofs = tid * 8;

  f32x4 acc[4][4] = {};
  const int nkt = K >> 5;

  gload16(gA0, &lsA[0][lofs]);
  gload16(gA1, &lsA[0][lofs + 2048]);
  gload16(gB0, &lsB[0][lofs]);
  gload16(gB1, &lsB[0][lofs + 2048]);
  __syncthreads();

  for (int kt = 0; kt < nkt; ++kt) {
    const int buf = kt & 1;
    if (kt + 1 < nkt) {
      const int ko = (kt + 1) << 5;
      gload16(gA0 + ko, &lsA[buf ^ 1][lofs]);
      gload16(gA1 + ko, &lsA[buf ^ 1][lofs + 2048]);
      gload16(gB0 + ko, &lsB[buf ^ 1][lofs]);
      gload16(gB1 + ko, &lsB[buf ^ 1][lofs + 2048]);
    }
    bf16x8 af[4], bfv[4];
#pragma unroll
    for (int mi = 0; mi < 4; ++mi) {
      const int r = wm * 64 + mi * 16 + lrow;
      const int ps = lk ^ ((r >> 1) & 3);
      af[mi] = *reinterpret_cast<const bf16x8*>(&lsA[buf][r * 32 + ps * 8]);
    }
#pragma unroll
    for (int ni = 0; ni < 4; ++ni) {
      const int r = wn * 64 + ni * 16 + lrow;
      const int ps = lk ^ ((r >> 1) & 3);
      bfv[ni] = *reinterpret_cast<const bf16x8*>(&lsB[buf][r * 32 + ps * 8]);
    }
#pragma unroll
    for (int mi = 0; mi < 4; ++mi)
#pragma unroll
      for (int ni = 0; ni < 4; ++ni)
        acc[mi][ni] = MFMA16(af[mi], bfv[ni], acc[mi][ni]);
    __syncthreads();
  }

#pragma unroll
  for (int mi = 0; mi < 4; ++mi) {
    const int row = m0 + wm * 64 + mi * 16 + lk * 4;
#pragma unroll
    for (int ni = 0; ni < 4; ++ni) {
      const int col = n0 + wn * 64 + ni * 16 + lrow;
#pragma unroll
      for (int rg = 0; rg < 4; ++rg)
        C[(size_t)(row + rg) * N + col] = acc[mi][ni][rg];
    }
  }
}

// ---------------------------------------------------------------------------
// QKV epilogue.  qkv raw = [4096][3072] f32 (q | k | v).  RMS-norm(q,k) +
// partial RoPE in fp32; q gets gain*(1/sqrt(128))*log2(e) folded in, stored
// hi/lo bf16 [.][256]; k plain bf16 [.][128]; v += ve_embed, plain bf16.
// ---------------------------------------------------------------------------
__global__ __launch_bounds__(256) void k_qkv_epi(
    const float* __restrict__ qkv, const float* __restrict__ ve,
    const float* __restrict__ qgain,
    const float* __restrict__ ctab, const float* __restrict__ stab,
    bf16_t* __restrict__ qn2, bf16_t* __restrict__ kn, bf16_t* __restrict__ vn)
{
  const int blk = blockIdx.x;           // b*2048 + t
  const int b = blk >> 11, t = blk & 2047;
  const int w = threadIdx.x >> 6, l = threadIdx.x & 63;
  const int i32 = l & 31;
  const float c = ctab[t * 32 + i32], s = stab[t * 32 + i32];
  const float EPS = 1.1920929e-07f;
  constexpr float SCALE_L2E = 0.088388347648318447f * 1.4426950408889634f;

  // Q: wave w handles heads w, w+4, w+8, w+12
#pragma unroll
  for (int it = 0; it < 4; ++it) {
    const int h = w + it * 4;
    const float* row = qkv + (size_t)blk * 3072 + h * 128;
    float x0 = row[l], x1 = row[l + 64];
    float ss = x0 * x0 + x1 * x1;
#pragma unroll
    for (int off = 32; off; off >>= 1) ss += __shfl_xor(ss, off);
    const float rn = rsqrtf(ss * (1.0f / 128.0f) + EPS);
    x0 *= rn; x1 *= rn;
    const float p = __shfl_xor(x0, 32);
    float xr = (l < 32) ? (x0 * c - p * s) : (p * s + x0 * c);
    const float g = qgain[h] * SCALE_L2E;
    xr *= g; x1 *= g;
    bf16_t* orow = qn2 + (((size_t)(b * 16 + h)) * 2048 + t) * 256;
    const bf16_t h0 = to_bf16(xr), h1 = to_bf16(x1);
    orow[l] = h0;        orow[128 + l] = to_bf16(xr - (float)h0);
    orow[l + 64] = h1;   orow[192 + l] = to_bf16(x1 - (float)h1);
  }
  // K: wave w -> kv head w (plain bf16)
  {
    const float* row = qkv + (size_t)blk * 3072 + 2048 + w * 128;
    float x0 = row[l], x1 = row[l + 64];
    float ss = x0 * x0 + x1 * x1;
#pragma unroll
    for (int off = 32; off; off >>= 1) ss += __shfl_xor(ss, off);
    const float rn = rsqrtf(ss * (1.0f / 128.0f) + EPS);
    x0 *= rn; x1 *= rn;
    const float p = __shfl_xor(x0, 32);
    const float xr = (l < 32) ? (x0 * c - p * s) : (p * s + x0 * c);
    bf16_t* orow = kn + (((size_t)(b * 4 + w)) * 2048 + t) * 128;
    orow[l] = to_bf16(xr);
    orow[l + 64] = to_bf16(x1);
  }
  // V: wave w -> kv head w ; v = vraw + ve
  {
    const float* row = qkv + (size_t)blk * 3072 + 2560 + w * 128;
    const float* verow = ve + (size_t)blk * 512 + w * 128;
    bf16_t* orow = vn + (((size_t)(b * 4 + w)) * 2048 + t) * 128;
    orow[l] = to_bf16(row[l] + verow[l]);
    orow[l + 64] = to_bf16(row[l + 64] + verow[l + 64]);
  }
}

// ---------------------------------------------------------------------------
// Causal GQA flash attention (unchanged from R5).
// ---------------------------------------------------------------------------
__global__ __launch_bounds__(256, 3) void k_attn(
    const bf16_t* __restrict__ qn2, const bf16_t* __restrict__ kn,
    const bf16_t* __restrict__ vn, bf16_t* __restrict__ y)
{
  __shared__ __align__(16) bf16_t lsK[64 * 136];      // 17408 B
  __shared__ __align__(16) bf16_t lsV[128 * 72];      // 18432 B
  __shared__ __align__(16) bf16_t lsPb[4][16 * 72];   //  9216 B
  const int qt = 31 - (int)blockIdx.y;  // longest first
  const int bh = blockIdx.x;            // 0..31
  const int b = bh >> 4, h = bh & 15, kvh = h >> 2;
  const int tid = threadIdx.x, w = tid >> 6, l = tid & 63;
  const int lrow = l & 15, lk = l >> 4;
  const int qbase = qt * 64 + w * 16;
  constexpr float NEG = -1e30f;
  bf16_t* lsP = lsPb[w];

  const bf16_t* qp = qn2 + ((size_t)(b * 16 + h) * 2048) * 256;
  bf16x8 aQh[4], aQl[4];
#pragma unroll
  for (int kf = 0; kf < 4; ++kf) {
    const size_t base = (size_t)(qbase + lrow) * 256 + kf * 32 + lk * 8;
    aQh[kf] = *reinterpret_cast<const bf16x8*>(qp + base);
    aQl[kf] = *reinterpret_cast<const bf16x8*>(qp + base + 128);
  }

  const bf16_t* kp = kn + ((size_t)(b * 4 + kvh) * 2048) * 128;
  const bf16_t* vp = vn + ((size_t)(b * 4 + kvh) * 2048) * 128;

  f32x4 o[8] = {};
  float mst[4], lst[4];
#pragma unroll
  for (int rg = 0; rg < 4; ++rg) { mst[rg] = NEG; lst[rg] = 0.f; }

  bf16x8 kreg[4], vreg[4];
  auto loadKV = [&](int t0) {
#pragma unroll
    for (int it = 0; it < 4; ++it) {
      const int cch = tid + it * 256;
      const size_t goff = (size_t)(t0 + (cch >> 4)) * 128 + (cch & 15) * 8;
      kreg[it] = *reinterpret_cast<const bf16x8*>(kp + goff);
      vreg[it] = *reinterpret_cast<const bf16x8*>(vp + goff);
    }
  };
  loadKV(0);

  const int ntiles = qt + 1;
  for (int tt = 0; tt < ntiles; ++tt) {
    __syncthreads();
#pragma unroll
    for (int it = 0; it < 4; ++it) {
      const int cch = tid + it * 256;
      const int r = cch >> 4, dg = cch & 15;
      *reinterpret_cast<bf16x8*>(&lsK[r * 136 + dg * 8]) = kreg[it];
      const int colb = r ^ ((dg & 7) << 3);
#pragma unroll
      for (int j = 0; j < 8; ++j) lsV[(dg * 8 + j) * 72 + colb] = vreg[it][j];
    }
    if (tt + 1 < ntiles) loadKV((tt + 1) * 64);
    __syncthreads();

    f32x4 sacc[4] = {};
#pragma unroll
    for (int cf = 0; cf < 4; ++cf) {
      const int krow = cf * 16 + lrow;
#pragma unroll
      for (int kf = 0; kf < 4; ++kf) {
        const bf16x8 bK = *reinterpret_cast<const bf16x8*>(
            &lsK[krow * 136 + kf * 32 + lk * 8]);
        sacc[cf] = MFMA16(aQh[kf], bK, sacc[cf]);
        sacc[cf] = MFMA16(aQl[kf], bK, sacc[cf]);
      }
    }

    if (tt == qt) {
#pragma unroll
      for (int rg = 0; rg < 4; ++rg) {
        const int qi = w * 16 + lk * 4 + rg;
#pragma unroll
        for (int cf = 0; cf < 4; ++cf)
          if (cf * 16 + lrow > qi) sacc[cf][rg] = NEG;
      }
    }
    float pmax[4];
#pragma unroll
    for (int rg = 0; rg < 4; ++rg) {
      float mx = fmaxf(fmaxf(sacc[0][rg], sacc[1][rg]),
                       fmaxf(sacc[2][rg], sacc[3][rg]));
      mx = fmaxf(mx, __shfl_xor(mx, 1));
      mx = fmaxf(mx, __shfl_xor(mx, 2));
      mx = fmaxf(mx, __shfl_xor(mx, 4));
      mx = fmaxf(mx, __shfl_xor(mx, 8));
      pmax[rg] = mx;
    }
    const bool grow = (pmax[0] > mst[0] + 8.f) | (pmax[1] > mst[1] + 8.f) |
                      (pmax[2] > mst[2] + 8.f) | (pmax[3] > mst[3] + 8.f);
    if (__any(grow)) {
#pragma unroll
      for (int rg = 0; rg < 4; ++rg) {
        const float mnew = fmaxf(mst[rg], pmax[rg]);
        const float alpha = exp2f(mst[rg] - mnew);
        mst[rg] = mnew;
        lst[rg] *= alpha;
#pragma unroll
        for (int df = 0; df < 8; ++df) o[df][rg] *= alpha;
      }
    }
#pragma unroll
    for (int rg = 0; rg < 4; ++rg) {
      float rsum = 0.f;
#pragma unroll
      for (int cf = 0; cf < 4; ++cf) {
        const float p = exp2f(sacc[cf][rg] - mst[rg]);
        sacc[cf][rg] = p;
        rsum += p;
      }
      rsum += __shfl_xor(rsum, 1);
      rsum += __shfl_xor(rsum, 2);
      rsum += __shfl_xor(rsum, 4);
      rsum += __shfl_xor(rsum, 8);
      lst[rg] += rsum;
    }

#pragma unroll
    for (int cf = 0; cf < 4; ++cf)
#pragma unroll
      for (int rg = 0; rg < 4; ++rg)
        lsP[(lk * 4 + rg) * 72 + cf * 16 + lrow] = to_bf16(sacc[cf][rg]);
#pragma unroll
    for (int k2 = 0; k2 < 2; ++k2) {
      const bf16x8 aP = *reinterpret_cast<const bf16x8*>(
          &lsP[lrow * 72 + k2 * 32 + lk * 8]);
#pragma unroll
      for (int df = 0; df < 8; ++df) {
        const int row = df * 16 + lrow;
        const int colb = (k2 * 32 + lk * 8) ^ (((row >> 3) & 7) << 3);
        const bf16x8 bV = *reinterpret_cast<const bf16x8*>(&lsV[row * 72 + colb]);
        o[df] = MFMA16(aP, bV, o[df]);
      }
    }
  }

#pragma unroll
  for (int rg = 0; rg < 4; ++rg) {
    const float inv = 1.0f / lst[rg];
    const int qi = qbase + lk * 4 + rg;
    const size_t rowoff = ((size_t)(b * 2048 + qi)) * 2048 + h * 128;
#pragma unroll
    for (int df = 0; df < 8; ++df)
      y[rowoff + df * 16 + lrow] = to_bf16(o[df][rg] * inv);
  }
}

// ---------------------------------------------------------------------------
extern "C" void kernel_launch(void* const* d_in, const int* in_sizes, int n_in,
                              void* d_out, int out_size, void* d_ws, size_t ws_size,
                              hipStream_t stream) {
  const float* x  = (const float*)d_in[0];
  const float* ve = (const float*)d_in[1];
  const float* Wq = (const float*)d_in[2];
  const float* Wk = (const float*)d_in[3];
  const float* Wv = (const float*)d_in[4];
  const float* Wp = (const float*)d_in[5];
  const float* qg = (const float*)d_in[6];
  float* out = (float*)d_out;

  char* ws = (char*)d_ws;
  size_t off = 0;
  auto alloc = [&](size_t bytes) -> char* {
    char* p = ws + off;
    off += (bytes + 255) & ~(size_t)255;
    return p;
  };

  bf16_t* x3     = (bf16_t*)alloc((size_t)4096 * 6144 * 2);  // [xh|xl|xh]; later qn2
  bf16_t* wqkv3  = (bf16_t*)alloc((size_t)3072 * 6144 * 2);  // rows: Wq|Wk|Wv, [Wh|Wh|Wl]
  bf16_t* wpb    = (bf16_t*)alloc((size_t)2048 * 2048 * 2);
  float*  qkvraw = (float*)alloc((size_t)4096 * 3072 * 4);   // later yb
  bf16_t* kn     = (bf16_t*)alloc((size_t)2 * 4 * 2048 * 128 * 2);
  bf16_t* vn     = (bf16_t*)alloc((size_t)2 * 4 * 2048 * 128 * 2);
  float*  ctab   = (float*)alloc((size_t)2048 * 32 * 4);
  float*  stab   = (float*)alloc((size_t)2048 * 32 * 4);
  bf16_t* qn2    = x3;               // x3 dead after QKV GEMM
  bf16_t* yb     = (bf16_t*)qkvraw;  // qkvraw dead after epilogue
  (void)ws_size; (void)in_sizes; (void)n_in; (void)out_size;

  k_split_x<<<2048, 256, 0, stream>>>(x, x3);
  k_split_w<<<1024, 256, 0, stream>>>(Wq, wqkv3, (long)2048 * 2048);
  k_split_w<<<512,  256, 0, stream>>>(Wk, wqkv3 + (size_t)2048 * 6144, (long)512 * 2048);
  k_split_w<<<512,  256, 0, stream>>>(Wv, wqkv3 + (size_t)2560 * 6144, (long)512 * 2048);
  k_cast_bf16<<<1024, 256, 0, stream>>>(Wp, wpb, (long)2048 * 2048);
  k_rope_tab<<<256, 256, 0, stream>>>(ctab, stab);

  // qkvraw = [xh|xl|xh]·[Wh|Wh|Wl]^T  (M=4096 N=3072 K=6144; 256x192 tiles,
  // grid 16x16 = 256 blocks = full machine)
  k_gemmQ<<<dim3(16, 16), 512, 0, stream>>>(x3, wqkv3, qkvraw, 4096, 3072, 6144, 6144, 6144);

  k_qkv_epi<<<4096, 256, 0, stream>>>(qkvraw, ve, qg, ctab, stab, qn2, kn, vn);

  k_attn<<<dim3(32, 32), 256, 0, stream>>>(qn2, kn, vn, yb);

  k_gemm_bt<<<dim3(16, 32), 256, 0, stream>>>(yb, wpb, out, 4096, 2048, 2048, 2048, 2048);
}